// Round 11
// baseline (1200.165 us; speedup 1.0000x reference)
//
#include <hip/hip_runtime.h>
#include <hip/hip_bf16.h>
#include <hip/hip_cooperative_groups.h>

namespace cg = cooperative_groups;

typedef unsigned short u16;
typedef short s8v __attribute__((ext_vector_type(8)));   // 8 bf16 (4 VGPRs)
typedef float f4v __attribute__((ext_vector_type(4)));

// L=1024, B=64, K=5, C=128, R=32, E=64, NL=6, NV=2, NF=4, NC=4, POOL=2
// All inputs/outputs f32. 18 k5-conv layers: 0=enc0, 1..5=enc, 6=decf0, 7..9=decf, 10..17=decv[c][j]
// Split-bf16: v = hi + lo; products use 3 MFMAs (hh, hl, lh).
// ONE cooperative persistent kernel: prep + 12 layers with grid.sync() between.

struct Ptrs { const float* p[25]; };

enum : int { ACT_PLANE = 2359296 };  // u16: 64*1152*32

__host__ __device__ inline int w1_off16(int l) {
  if (l == 0) return 0;
  if (l <= 5) return 4096 + (l - 1) * 20480;
  if (l == 6) return 106496;
  if (l <= 9) return 147456 + (l - 7) * 20480;
  return 208896 + (l - 10) * 20480;
}

enum : int {
  OFF_W1H = 0,
  OFF_W1L = 186368,
  OFF_W2H = 372736,
  OFF_W2L = 409600,
  OFF_CWT = 446464,
  OFF_B1  = 458752,
  OFF_B2  = 461056,
  OFF_CB  = 461632,
  OFF_VCW = 461696,
  OFF_VCB = 462464,
  OFF_PACC = 524288,    // f32 [64][64][512]
  OFF_FACC = 2621440,   // f32 [64][1024]
  OFF_ACT0 = 2752512,   // u16 H[64][1152][32] then L plane
  OFF_ACT1 = 5111808,
};

__device__ __host__ inline int w1_cin(int l) { return l == 0 ? 1 : (l == 6 ? 64 : 32); }

__device__ inline const float* w1_src(const Ptrs& in, int l) {
  if (l == 0) return in.p[1];
  if (l <= 5) return in.p[5] + (l - 1) * 20480;
  if (l == 6) return in.p[11];
  if (l <= 9) return in.p[15] + (l - 7) * 20480;
  return in.p[19] + (l - 10) * 20480;
}
__device__ inline const float* w2_src(const Ptrs& in, int l) {
  if (l == 0) return in.p[3];
  if (l <= 5) return in.p[7] + (l - 1) * 4096;
  if (l == 6) return in.p[13];
  if (l <= 9) return in.p[17] + (l - 7) * 4096;
  return in.p[21] + (l - 10) * 4096;
}
__device__ inline const float* b1_src(const Ptrs& in, int l) {
  if (l == 0) return in.p[2];
  if (l <= 5) return in.p[6] + (l - 1) * 128;
  if (l == 6) return in.p[12];
  if (l <= 9) return in.p[16] + (l - 7) * 128;
  return in.p[20] + (l - 10) * 128;
}
__device__ inline const float* b2_src(const Ptrs& in, int l) {
  if (l == 0) return in.p[4];
  if (l <= 5) return in.p[8] + (l - 1) * 32;
  if (l == 6) return in.p[14];
  if (l <= 9) return in.p[18] + (l - 7) * 32;
  return in.p[22] + (l - 10) * 32;
}

__device__ inline u16 f2b(float v) {
  unsigned b = __float_as_uint(v);
  b += 0x7FFFu + ((b >> 16) & 1u);
  return (u16)(b >> 16);
}
__device__ inline float b2fl(u16 h) { return __uint_as_float((unsigned)h << 16); }
__device__ inline void splitf(float v, u16& h, u16& l) {
  h = f2b(v);
  l = f2b(v - b2fl(h));
}

// ---- prep slice (job 0..39, sl 0..7) ----
__device__ void prep_body(int job, int sl, int t, const Ptrs& in, float* __restrict__ ws) {
  u16* w1h = (u16*)(ws + OFF_W1H);
  u16* w1l = (u16*)(ws + OFF_W1L);
  u16* w2h = (u16*)(ws + OFF_W2H);
  u16* w2l = (u16*)(ws + OFF_W2L);
  u16* cwH = (u16*)(ws + OFF_CWT);
  u16* cwL = cwH + 12288;
  if (job == 0) {
    if (sl == 0) {
      const float* src = w1_src(in, 0);
      for (int i = t; i < 4096; i += 256) {
        const int co = i >> 5, q = i & 31;
        const float v = (q < 5) ? src[co * 5 + q] : 0.f;
        u16 hh, ll; splitf(v, hh, ll);
        w1h[i] = hh; w1l[i] = ll;
      }
    }
  } else if (job < 18) {
    const int cin = w1_cin(job);
    const int lc = (cin == 64) ? 6 : 5;
    const float* src = w1_src(in, job);
    u16* dh = w1h + w1_off16(job);
    u16* dl = w1l + w1_off16(job);
    const int n = 5 * 128 * cin;
    for (int i = t + sl * 256; i < n; i += 2048) {
      const int tap = i >> (7 + lc);
      const int co = (i >> lc) & 127;
      const int ci = i & (cin - 1);
      u16 hh, ll; splitf(src[(co * cin + ci) * 5 + tap], hh, ll);
      dh[i] = hh; dl[i] = ll;
    }
  } else if (job < 36) {
    const int l = job - 18;
    const float* src = w2_src(in, l);
    for (int i = t + sl * 256; i < 4096; i += 2048) {
      u16 hh, ll; splitf(src[i], hh, ll);
      w2h[l * 4096 + i] = hh; w2l[l * 4096 + i] = ll;
    }
  } else if (job == 36) {
    const float* src = in.p[9];
    for (int i = t + sl * 256; i < 12288; i += 2048) {
      u16 hh, ll; splitf(src[i], hh, ll);
      cwH[i] = hh; cwL[i] = ll;
    }
  } else if (job == 37) {
    if (sl == 0) {
      for (int i = t; i < 18 * 128; i += 256) {
        const int l = i >> 7, r = i & 127;
        ws[OFF_B1 + i] = b1_src(in, l)[r];
      }
      for (int i = t; i < 18 * 32; i += 256) {
        const int l = i >> 5, r = i & 31;
        ws[OFF_B2 + i] = b2_src(in, l)[r];
      }
      for (int i = t; i < 64; i += 256) ws[OFF_CB + i] = in.p[10][i];
      for (int i = t; i < 768; i += 256) ws[OFF_VCW + i] = in.p[23][i];
      for (int i = t; i < 4; i += 256) ws[OFF_VCB + i] = in.p[24][i];
    }
  } else {
    u16* A = (u16*)(ws + (job == 38 ? OFF_ACT0 : OFF_ACT1));
    const uint4 z = make_uint4(0, 0, 0, 0);
    for (int i = t; i < 8192; i += 256) {
      const int cid = sl * 8192 + i;
      const int p = cid >> 15;
      const int r = cid & 32767;
      const int b = r >> 9;
      const int r2 = r & 511;
      const int pc = r2 >> 2;
      const int slot = r2 & 3;
      const int col = (pc < 64) ? pc : (1024 + pc);
      *(uint4*)&A[p * ACT_PLANE + (b * 1152 + col) * 32 + slot * 8] = z;
    }
  }
}

// ---- layer body: conv k5 (CIN->128) + ReLU + 1x1 (128->32) + ReLU + epilogue ----
// S=0: f32 x [B][1025]; S=1: u16 act padded; S=2: f32 pacc upsampled
// epi (runtime): 1=pacc-init 2=pacc-accum 3=facc-init 4=facc-accum 5=facc+store-out
template <int CIN, int S, bool VAR>
__device__ void layer_body(
    int tile, const void* __restrict__ src,
    const u16* __restrict__ w1h, const u16* __restrict__ w1l,
    const u16* __restrict__ w2h, const u16* __restrict__ w2l,
    const float* __restrict__ b1f, const float* __restrict__ b2f,
    u16* __restrict__ outH, int dil,
    const float* __restrict__ x, int jvar, int jf, int epi,
    const u16* __restrict__ cwtbH, const u16* __restrict__ cwtbL,
    const float* __restrict__ cb, float* __restrict__ pacc,
    const float* __restrict__ vcw, const float* __restrict__ vcb,
    float* __restrict__ facc, float* __restrict__ fout,
    u16* lds) {
  constexpr int HS = 136;
  u16* hH = lds;
  u16* hL = lds + 64 * HS;

  const int tid = threadIdx.x;
  const int lane = tid & 63;
  const int wid = __builtin_amdgcn_readfirstlane(tid >> 6);
  const int l15 = lane & 15;
  const int g = lane >> 4;
  const int col0 = (tile & 15) * 64;
  const int b = tile >> 4;

  __syncthreads();   // LDS may still be read by previous tile's epilogue

  if (VAR) {
    int c = (int)x[b * 1025 + 1024];
    c = c < 0 ? 0 : (c > 3 ? 3 : c);
    c = __builtin_amdgcn_readfirstlane(c);
    const int lo_ = c * 2 + jvar;
    w1h += lo_ * 20480; w1l += lo_ * 20480;
    w2h += lo_ * 4096;  w2l += lo_ * 4096;
    b1f += lo_ * 128;   b2f += lo_ * 32;
  }

  const int co0 = wid * 32;
  const f4v zf = {0.f, 0.f, 0.f, 0.f};
  const s8v z8 = {0, 0, 0, 0, 0, 0, 0, 0};
  f4v acc[2][4];
#pragma unroll
  for (int rt = 0; rt < 2; ++rt)
#pragma unroll
    for (int ct = 0; ct < 4; ++ct) acc[rt][ct] = zf;

  if (S == 1) {
    // stage 192-col act halo tile into LDS (slot-XOR swizzle)
    const u16* aH = (const u16*)src;
    const int gbase = (b * 1152 + col0) * 32;
#pragma unroll
    for (int k = 0; k < 3; ++k) {
      const int c2 = tid + k * 256;
      const int q = c2 >> 2, slot = c2 & 3;
      const uint4 v = *(const uint4*)(aH + gbase + c2 * 8);
      *(uint4*)&lds[q * 32 + ((slot ^ (q & 3)) << 3)] = v;
    }
#pragma unroll
    for (int k = 0; k < 3; ++k) {
      const int c2 = tid + k * 256;
      const int q = c2 >> 2, slot = c2 & 3;
      const uint4 v = *(const uint4*)(aH + ACT_PLANE + gbase + c2 * 8);
      *(uint4*)&lds[6144 + q * 32 + ((slot ^ (q & 3)) << 3)] = v;
    }
    __syncthreads();

#pragma unroll
    for (int tap = 0; tap < 5; ++tap) {
      s8v ah[2], al[2];
#pragma unroll
      for (int rt = 0; rt < 2; ++rt) {
        const int row = co0 + rt * 16 + l15;
        ah[rt] = *(const s8v*)(w1h + (tap * 128 + row) * 32 + 8 * g);
        al[rt] = *(const s8v*)(w1l + (tap * 128 + row) * 32 + 8 * g);
      }
#pragma unroll
      for (int ct = 0; ct < 4; ++ct) {
        const int q = ct * 16 + l15 + (tap - 2) * dil + 64;
        const int off = q * 32 + ((g ^ (q & 3)) << 3);
        const s8v bh = *(const s8v*)&lds[off];
        const s8v bl = *(const s8v*)&lds[6144 + off];
#pragma unroll
        for (int rt = 0; rt < 2; ++rt) {
          acc[rt][ct] = __builtin_amdgcn_mfma_f32_16x16x32_bf16(ah[rt], bh, acc[rt][ct], 0, 0, 0);
          acc[rt][ct] = __builtin_amdgcn_mfma_f32_16x16x32_bf16(ah[rt], bl, acc[rt][ct], 0, 0, 0);
          acc[rt][ct] = __builtin_amdgcn_mfma_f32_16x16x32_bf16(al[rt], bh, acc[rt][ct], 0, 0, 0);
        }
      }
    }
    __syncthreads();   // act tile dead; lds reused for h
  } else if (S == 0) {
    s8v ah[2], al[2];
#pragma unroll
    for (int rt = 0; rt < 2; ++rt) {
      const int row = co0 + rt * 16 + l15;
      ah[rt] = *(const s8v*)(w1h + row * 32 + 8 * g);
      al[rt] = *(const s8v*)(w1l + row * 32 + 8 * g);
    }
    const float* xf = (const float*)src;
#pragma unroll
    for (int ct = 0; ct < 4; ++ct) {
      s8v bh = z8, bl = z8;
#pragma unroll
      for (int j = 0; j < 8; ++j) {
        const int q = 8 * g + j;
        const int m = col0 + ct * 16 + l15 + (q - 2);
        float v = (q < 5 && (unsigned)m < 1024u) ? xf[b * 1025 + m] : 0.f;
        u16 hh, ll; splitf(v, hh, ll);
        bh[j] = (short)hh; bl[j] = (short)ll;
      }
#pragma unroll
      for (int rt = 0; rt < 2; ++rt) {
        acc[rt][ct] = __builtin_amdgcn_mfma_f32_16x16x32_bf16(ah[rt], bh, acc[rt][ct], 0, 0, 0);
        acc[rt][ct] = __builtin_amdgcn_mfma_f32_16x16x32_bf16(ah[rt], bl, acc[rt][ct], 0, 0, 0);
        acc[rt][ct] = __builtin_amdgcn_mfma_f32_16x16x32_bf16(al[rt], bh, acc[rt][ct], 0, 0, 0);
      }
    }
  } else {
    const float* pc = (const float*)src;
#pragma unroll
    for (int tap = 0; tap < 5; ++tap) {
#pragma unroll
      for (int ch = 0; ch < 2; ++ch) {
        s8v ah[2], al[2];
#pragma unroll
        for (int rt = 0; rt < 2; ++rt) {
          const int row = co0 + rt * 16 + l15;
          ah[rt] = *(const s8v*)(w1h + (tap * 128 + row) * 64 + ch * 32 + 8 * g);
          al[rt] = *(const s8v*)(w1l + (tap * 128 + row) * 64 + ch * 32 + 8 * g);
        }
#pragma unroll
        for (int ct = 0; ct < 4; ++ct) {
          const int m = col0 + ct * 16 + l15 + (tap - 2) * dil;
          s8v bh = z8, bl = z8;
          if ((unsigned)m < 1024u) {
            const int pcol = m >> 1;
#pragma unroll
            for (int j = 0; j < 8; ++j) {
              const float v = pc[b * 32768 + (ch * 32 + 8 * g + j) * 512 + pcol];
              u16 hh, ll; splitf(v, hh, ll);
              bh[j] = (short)hh; bl[j] = (short)ll;
            }
          }
#pragma unroll
          for (int rt = 0; rt < 2; ++rt) {
            acc[rt][ct] = __builtin_amdgcn_mfma_f32_16x16x32_bf16(ah[rt], bh, acc[rt][ct], 0, 0, 0);
            acc[rt][ct] = __builtin_amdgcn_mfma_f32_16x16x32_bf16(ah[rt], bl, acc[rt][ct], 0, 0, 0);
            acc[rt][ct] = __builtin_amdgcn_mfma_f32_16x16x32_bf16(al[rt], bh, acc[rt][ct], 0, 0, 0);
          }
        }
      }
    }
  }

  // h = relu(conv1 + b1) -> hi/lo planes in LDS [col][c2]
#pragma unroll
  for (int rt = 0; rt < 2; ++rt) {
#pragma unroll
    for (int ct = 0; ct < 4; ++ct) {
      const int colw = ct * 16 + l15;
      unsigned ph0 = 0, ph1 = 0, pl0 = 0, pl1 = 0;
#pragma unroll
      for (int reg = 0; reg < 4; ++reg) {
        const int c2 = co0 + rt * 16 + 4 * g + reg;
        const float hv = fmaxf(acc[rt][ct][reg] + b1f[c2], 0.f);
        u16 hh, ll; splitf(hv, hh, ll);
        if (reg == 0)      { ph0 = hh;                  pl0 = ll; }
        else if (reg == 1) { ph0 |= (unsigned)hh << 16; pl0 |= (unsigned)ll << 16; }
        else if (reg == 2) { ph1 = hh;                  pl1 = ll; }
        else               { ph1 |= (unsigned)hh << 16; pl1 |= (unsigned)ll << 16; }
      }
      const int base = colw * HS + co0 + rt * 16 + 4 * g;
      *(uint2*)&hH[base] = make_uint2(ph0, ph1);
      *(uint2*)&hL[base] = make_uint2(pl0, pl1);
    }
  }
  __syncthreads();

  // conv2: wave handles its 16-col slice
  f4v acc2[2];
  acc2[0] = zf; acc2[1] = zf;
  const int colw2 = wid * 16 + l15;
#pragma unroll
  for (int ks = 0; ks < 4; ++ks) {
    const int k0 = ks * 32 + 8 * g;
    const s8v bh = *(const s8v*)&hH[colw2 * HS + k0];
    const s8v bl = *(const s8v*)&hL[colw2 * HS + k0];
#pragma unroll
    for (int rt = 0; rt < 2; ++rt) {
      const int row = rt * 16 + l15;
      const s8v ah2 = *(const s8v*)(w2h + row * 128 + k0);
      const s8v al2 = *(const s8v*)(w2l + row * 128 + k0);
      acc2[rt] = __builtin_amdgcn_mfma_f32_16x16x32_bf16(ah2, bh, acc2[rt], 0, 0, 0);
      acc2[rt] = __builtin_amdgcn_mfma_f32_16x16x32_bf16(ah2, bl, acc2[rt], 0, 0, 0);
      acc2[rt] = __builtin_amdgcn_mfma_f32_16x16x32_bf16(al2, bh, acc2[rt], 0, 0, 0);
    }
  }

  // epilogue: act store + fused pacc/facc
  u16* outL = outH + ACT_PLANE;
  float vv[8];
#pragma unroll
  for (int rt = 0; rt < 2; ++rt) {
    unsigned ph0 = 0, ph1 = 0, pl0 = 0, pl1 = 0;
#pragma unroll
    for (int reg = 0; reg < 4; ++reg) {
      const int r = rt * 16 + 4 * g + reg;
      const float v = fmaxf(acc2[rt][reg] + b2f[r], 0.f);
      vv[rt * 4 + reg] = v;
      u16 hh, ll; splitf(v, hh, ll);
      if (reg == 0)      { ph0 = hh;                  pl0 = ll; }
      else if (reg == 1) { ph0 |= (unsigned)hh << 16; pl0 |= (unsigned)ll << 16; }
      else if (reg == 2) { ph1 = hh;                  pl1 = ll; }
      else               { ph1 |= (unsigned)hh << 16; pl1 |= (unsigned)ll << 16; }
    }
    if (epi != 5) {
      const int ob = (b * 1152 + 64 + col0 + colw2) * 32 + rt * 16 + 4 * g;
      *(uint2*)&outH[ob] = make_uint2(ph0, ph1);
      *(uint2*)&outL[ob] = make_uint2(pl0, pl1);
    }
  }
  __syncthreads();   // conv2 LDS reads done; lds reusable

  if (epi <= 2) {
    u16* spH = lds;
    u16* spL = lds + 1280;
    float vx[8];
#pragma unroll
    for (int i = 0; i < 8; ++i) vx[i] = __shfl_xor(vv[i], 1);
    if (!(l15 & 1)) {
      const int pl = colw2 >> 1;
#pragma unroll
      for (int i = 0; i < 8; ++i) {
        const int rt = i >> 2, reg = i & 3;
        const int r = rt * 16 + 4 * g + reg;
        const float pv = 0.5f * (vv[i] + vx[i]);
        u16 hh, ll; splitf(pv, hh, ll);
        spH[pl * 40 + r] = hh; spL[pl * 40 + r] = ll;
      }
    }
    __syncthreads();
    const u16* cwH = cwtbH + jf * 32;
    const u16* cwL = cwtbL + jf * 32;
    const s8v aH = *(const s8v*)(cwH + (wid * 16 + l15) * 192 + 8 * g);
    const s8v aL = *(const s8v*)(cwL + (wid * 16 + l15) * 192 + 8 * g);
#pragma unroll
    for (int pt = 0; pt < 2; ++pt) {
      const s8v bH = *(const s8v*)(spH + (pt * 16 + l15) * 40 + 8 * g);
      const s8v bL = *(const s8v*)(spL + (pt * 16 + l15) * 40 + 8 * g);
      f4v p = zf;
      p = __builtin_amdgcn_mfma_f32_16x16x32_bf16(aH, bH, p, 0, 0, 0);
      p = __builtin_amdgcn_mfma_f32_16x16x32_bf16(aH, bL, p, 0, 0, 0);
      p = __builtin_amdgcn_mfma_f32_16x16x32_bf16(aL, bH, p, 0, 0, 0);
#pragma unroll
      for (int reg = 0; reg < 4; ++reg) {
        const int e = wid * 16 + 4 * g + reg;
        const int pg = (col0 >> 1) + pt * 16 + l15;
        float* dst = pacc + b * 32768 + e * 512 + pg;
        const float old = (epi == 1) ? cb[e] : *dst;
        *dst = old + p[reg];
      }
    }
  } else {
    float* ft = (float*)lds;
#pragma unroll
    for (int i = 0; i < 8; ++i) {
      const int rt = i >> 2, reg = i & 3;
      const int r = rt * 16 + 4 * g + reg;
      ft[r * 64 + colw2] = vv[i];
    }
    __syncthreads();
    if (wid == 0) {
      int c = (int)x[b * 1025 + 1024];
      c = c < 0 ? 0 : (c > 3 ? 3 : c);
      c = __builtin_amdgcn_readfirstlane(c);
      const float* w = vcw + c * 192 + jf * 32;
      float a = 0.f;
#pragma unroll
      for (int r = 0; r < 32; ++r) a = fmaf(w[r], ft[r * 64 + lane], a);
      float* fd = facc + b * 1024 + col0 + lane;
      a += (epi == 3) ? vcb[c] : *fd;
      if (epi == 5) fout[b * 1024 + col0 + lane] = a;
      else          *fd = a;
    }
  }
}

// ---- the persistent cooperative megakernel ----
__global__ __launch_bounds__(256, 4) void mega_k(Ptrs in, float* __restrict__ ws,
                                                 float* __restrict__ outp) {
  __shared__ __align__(16) u16 lds[2 * 64 * 136];
  cg::grid_group grid = cg::this_grid();
  const float* x = in.p[0];
  float* pacc = ws + OFF_PACC;
  float* facc = ws + OFF_FACC;
  u16* A0 = (u16*)(ws + OFF_ACT0);
  u16* A1 = (u16*)(ws + OFF_ACT1);
  const u16* w1hb = (const u16*)(ws + OFF_W1H);
  const u16* w1lb = (const u16*)(ws + OFF_W1L);
  const u16* w2hb = (const u16*)(ws + OFF_W2H);
  const u16* w2lb = (const u16*)(ws + OFF_W2L);
  const u16* cwtbH = (const u16*)(ws + OFF_CWT);
  const u16* cwtbL = cwtbH + 12288;
  const float* b1b = ws + OFF_B1;
  const float* b2b = ws + OFF_B2;
  const float* cb = ws + OFF_CB;
  const float* vcw = ws + OFF_VCW;
  const float* vcb = ws + OFF_VCB;

  // phase 0: prep (40 jobs x 8 slices)
  for (int w = blockIdx.x; w < 320; w += gridDim.x)
    prep_body(w >> 3, w & 7, threadIdx.x, in, ws);
  grid.sync();

  // enc0
  for (int t = blockIdx.x; t < 1024; t += gridDim.x)
    layer_body<1, 0, false>(t, x, w1hb + w1_off16(0), w1lb + w1_off16(0),
        w2hb, w2lb, b1b, b2b, A0, 1, x, 0, 0, 1,
        cwtbH, cwtbL, cb, pacc, vcw, vcb, facc, outp, lds);
  grid.sync();

  u16* cur = A0; u16* nxt = A1;
  for (int j = 1; j <= 5; ++j) {
    for (int t = blockIdx.x; t < 1024; t += gridDim.x)
      layer_body<32, 1, false>(t, cur, w1hb + w1_off16(j), w1lb + w1_off16(j),
          w2hb + j * 4096, w2lb + j * 4096, b1b + j * 128, b2b + j * 32,
          nxt, 1 << j, x, 0, j, 2,
          cwtbH, cwtbL, cb, pacc, vcw, vcb, facc, outp, lds);
    grid.sync();
    u16* tmp = cur; cur = nxt; nxt = tmp;
  }

  // decf0 (reads pacc, nearest-upsample)
  for (int t = blockIdx.x; t < 1024; t += gridDim.x)
    layer_body<64, 2, false>(t, pacc, w1hb + w1_off16(6), w1lb + w1_off16(6),
        w2hb + 6 * 4096, w2lb + 6 * 4096, b1b + 6 * 128, b2b + 6 * 32,
        A0, 32, x, 0, 0, 3,
        cwtbH, cwtbL, cb, pacc, vcw, vcb, facc, outp, lds);
  grid.sync();

  cur = A0; nxt = A1;
  for (int j = 1; j <= 3; ++j) {
    for (int t = blockIdx.x; t < 1024; t += gridDim.x)
      layer_body<32, 1, false>(t, cur, w1hb + w1_off16(6 + j), w1lb + w1_off16(6 + j),
          w2hb + (6 + j) * 4096, w2lb + (6 + j) * 4096,
          b1b + (6 + j) * 128, b2b + (6 + j) * 32,
          nxt, 1 << (5 - j), x, 0, j, 4,
          cwtbH, cwtbL, cb, pacc, vcw, vcb, facc, outp, lds);
    grid.sync();
    u16* tmp = cur; cur = nxt; nxt = tmp;
  }

  // variable decoder (per-sample weights, base = layer 10)
  for (int t = blockIdx.x; t < 1024; t += gridDim.x)
    layer_body<32, 1, true>(t, cur, w1hb + w1_off16(10), w1lb + w1_off16(10),
        w2hb + 10 * 4096, w2lb + 10 * 4096, b1b + 10 * 128, b2b + 10 * 32,
        nxt, 2, x, 0, 4, 4,
        cwtbH, cwtbL, cb, pacc, vcw, vcb, facc, outp, lds);
  grid.sync();
  { u16* tmp = cur; cur = nxt; nxt = tmp; }
  for (int t = blockIdx.x; t < 1024; t += gridDim.x)
    layer_body<32, 1, true>(t, cur, w1hb + w1_off16(10), w1lb + w1_off16(10),
        w2hb + 10 * 4096, w2lb + 10 * 4096, b1b + 10 * 128, b2b + 10 * 32,
        nxt, 1, x, 1, 5, 5,
        cwtbH, cwtbL, cb, pacc, vcw, vcb, facc, outp, lds);
}

extern "C" void kernel_launch(void* const* d_in, const int* in_sizes, int n_in,
                              void* d_out, int out_size, void* d_ws, size_t ws_size,
                              hipStream_t stream) {
  (void)in_sizes; (void)n_in; (void)out_size; (void)ws_size;
  Ptrs P;
  for (int i = 0; i < 25; ++i) P.p[i] = (const float*)d_in[i];
  float* ws = (float*)d_ws;
  float* outp = (float*)d_out;

  int nCU = 256;
  hipDeviceGetAttribute(&nCU, hipDeviceAttributeMultiprocessorCount, 0);
  int perCU = 0;
  hipOccupancyMaxActiveBlocksPerMultiprocessor(&perCU, mega_k, 256, 0);
  if (perCU < 1) perCU = 1;
  long grid = (long)perCU * nCU;
  if (grid > 1024) grid = 1024;

  void* kargs[] = {(void*)&P, (void*)&ws, (void*)&outp};
  hipLaunchCooperativeKernel(mega_k, dim3((unsigned)grid), dim3(256), kargs, 0, stream);
}

// Round 12
// 370.968 us; speedup vs baseline: 3.2352x; 3.2352x over previous
//
#include <hip/hip_runtime.h>
#include <hip/hip_bf16.h>

typedef unsigned short u16;
typedef short s8v __attribute__((ext_vector_type(8)));   // 8 bf16 (4 VGPRs)
typedef float f4v __attribute__((ext_vector_type(4)));

// L=1024, B=64, K=5, C=128, R=32, E=64, NL=6, NV=2, NF=4, NC=4, POOL=2
// All inputs/outputs f32. 18 k5-conv layers: 0=enc0, 1..5=enc, 6=decf0, 7..9=decf, 10..17=decv[c][j]
// Split-bf16: v = hi + lo; products use 3 MFMAs (hh, hl, lh).
// Multi-dispatch (round-8 structure; grid.sync megakernel falsified in r11).
// pacc layout [b][pg 512][e 64] (channel-contiguous); h-tile 32KB XOR-swizzled -> 5 blocks/CU.

struct Ptrs { const float* p[25]; };

enum : int { ACT_PLANE = 2359296 };  // u16: 64*1152*32

__host__ __device__ inline int w1_off16(int l) {
  if (l == 0) return 0;                        // enc0: [128][32 qpad] = 4096
  if (l <= 5) return 4096 + (l - 1) * 20480;   // [5][128][32]
  if (l == 6) return 106496;                   // decf0: [5][128][64] = 40960
  if (l <= 9) return 147456 + (l - 7) * 20480;
  return 208896 + (l - 10) * 20480;            // decv -> ends 372736
}

enum : int {
  OFF_W1H = 0,          // u16 372736
  OFF_W1L = 186368,
  OFF_W2H = 372736,     // u16 18*32*128
  OFF_W2L = 409600,
  OFF_CWT = 446464,     // u16 cwtbH [64][192] then cwtbL [64][192]
  OFF_B1  = 458752,     // f32 18*128
  OFF_B2  = 461056,     // f32 18*32
  OFF_CB  = 461632,     // f32 64
  OFF_VCW = 461696,     // f32 4*192
  OFF_VCB = 462464,     // f32 4
  OFF_PACC = 524288,    // f32 [64][512 pg][64 e]
  OFF_FACC = 2621440,   // f32 [64][1024]
  OFF_ACT0 = 2752512,   // u16 H[64][1152][32] then L plane
  OFF_ACT1 = 5111808,
};

__device__ __host__ inline int w1_cin(int l) { return l == 0 ? 1 : (l == 6 ? 64 : 32); }

__device__ inline const float* w1_src(const Ptrs& in, int l) {
  if (l == 0) return in.p[1];
  if (l <= 5) return in.p[5] + (l - 1) * 20480;
  if (l == 6) return in.p[11];
  if (l <= 9) return in.p[15] + (l - 7) * 20480;
  return in.p[19] + (l - 10) * 20480;
}
__device__ inline const float* w2_src(const Ptrs& in, int l) {
  if (l == 0) return in.p[3];
  if (l <= 5) return in.p[7] + (l - 1) * 4096;
  if (l == 6) return in.p[13];
  if (l <= 9) return in.p[17] + (l - 7) * 4096;
  return in.p[21] + (l - 10) * 4096;
}
__device__ inline const float* b1_src(const Ptrs& in, int l) {
  if (l == 0) return in.p[2];
  if (l <= 5) return in.p[6] + (l - 1) * 128;
  if (l == 6) return in.p[12];
  if (l <= 9) return in.p[16] + (l - 7) * 128;
  return in.p[20] + (l - 10) * 128;
}
__device__ inline const float* b2_src(const Ptrs& in, int l) {
  if (l == 0) return in.p[4];
  if (l <= 5) return in.p[8] + (l - 1) * 32;
  if (l == 6) return in.p[14];
  if (l <= 9) return in.p[18] + (l - 7) * 32;
  return in.p[22] + (l - 10) * 32;
}

__device__ inline u16 f2b(float v) {
  unsigned b = __float_as_uint(v);
  b += 0x7FFFu + ((b >> 16) & 1u);
  return (u16)(b >> 16);
}
__device__ inline float b2fl(u16 h) { return __uint_as_float((unsigned)h << 16); }
__device__ inline void splitf(float v, u16& h, u16& l) {
  h = f2b(v);
  l = f2b(v - b2fl(h));
}

// ---- weight prep + act pad zeroing: grid (40, 8) ----
__global__ __launch_bounds__(256) void prep_k(Ptrs in, float* __restrict__ ws) {
  const int job = blockIdx.x;
  const int sl = blockIdx.y;
  const int t = threadIdx.x;
  u16* w1h = (u16*)(ws + OFF_W1H);
  u16* w1l = (u16*)(ws + OFF_W1L);
  u16* w2h = (u16*)(ws + OFF_W2H);
  u16* w2l = (u16*)(ws + OFF_W2L);
  u16* cwH = (u16*)(ws + OFF_CWT);
  u16* cwL = cwH + 12288;
  if (job == 0) {
    if (sl == 0) {
      const float* src = w1_src(in, 0);
      for (int i = t; i < 4096; i += 256) {
        const int co = i >> 5, q = i & 31;
        const float v = (q < 5) ? src[co * 5 + q] : 0.f;
        u16 hh, ll; splitf(v, hh, ll);
        w1h[i] = hh; w1l[i] = ll;
      }
    }
  } else if (job < 18) {
    // w1 [Cout][Cin][5] -> [tap 5][co 128][ci cin]
    const int cin = w1_cin(job);
    const int lc = (cin == 64) ? 6 : 5;
    const float* src = w1_src(in, job);
    u16* dh = w1h + w1_off16(job);
    u16* dl = w1l + w1_off16(job);
    const int n = 5 * 128 * cin;
    for (int i = t + sl * 256; i < n; i += 2048) {
      const int tap = i >> (7 + lc);
      const int co = (i >> lc) & 127;
      const int ci = i & (cin - 1);
      u16 hh, ll; splitf(src[(co * cin + ci) * 5 + tap], hh, ll);
      dh[i] = hh; dl[i] = ll;
    }
  } else if (job < 36) {
    const int l = job - 18;
    const float* src = w2_src(in, l);
    for (int i = t + sl * 256; i < 4096; i += 2048) {
      u16 hh, ll; splitf(src[i], hh, ll);
      w2h[l * 4096 + i] = hh; w2l[l * 4096 + i] = ll;
    }
  } else if (job == 36) {
    const float* src = in.p[9];
    for (int i = t + sl * 256; i < 12288; i += 2048) {
      u16 hh, ll; splitf(src[i], hh, ll);
      cwH[i] = hh; cwL[i] = ll;
    }
  } else if (job == 37) {
    if (sl == 0) {
      for (int i = t; i < 18 * 128; i += 256) {
        const int l = i >> 7, r = i & 127;
        ws[OFF_B1 + i] = b1_src(in, l)[r];
      }
      for (int i = t; i < 18 * 32; i += 256) {
        const int l = i >> 5, r = i & 31;
        ws[OFF_B2 + i] = b2_src(in, l)[r];
      }
      for (int i = t; i < 64; i += 256) ws[OFF_CB + i] = in.p[10][i];
      for (int i = t; i < 768; i += 256) ws[OFF_VCW + i] = in.p[23][i];
      for (int i = t; i < 4; i += 256) ws[OFF_VCB + i] = in.p[24][i];
    }
  } else {
    // jobs 38/39: zero the pad columns of A0/A1 (both planes)
    u16* A = (u16*)(ws + (job == 38 ? OFF_ACT0 : OFF_ACT1));
    const uint4 z = make_uint4(0, 0, 0, 0);
    for (int i = t; i < 8192; i += 256) {
      const int cid = sl * 8192 + i;
      const int p = cid >> 15;
      const int r = cid & 32767;
      const int b = r >> 9;
      const int r2 = r & 511;
      const int pc = r2 >> 2;
      const int slot = r2 & 3;
      const int col = (pc < 64) ? pc : (1024 + pc);
      *(uint4*)&A[p * ACT_PLANE + (b * 1152 + col) * 32 + slot * 8] = z;
    }
  }
}

// ---- fused block: conv k5 (CIN->128) + ReLU + 1x1 (128->32) + ReLU + epilogue ----
// S=0: f32 x [B][1025]; S=1: u16 act padded; S=2: f32 pacc [b][512][64] upsampled
// EPI: 1=pacc-init 2=pacc-accum 3=facc-init 4=facc-accum 5=facc+store-out
template <int CIN, int S, bool VAR, int EPI>
__global__ __launch_bounds__(256, 5) void blk_k(
    const void* __restrict__ src,
    const u16* __restrict__ w1h, const u16* __restrict__ w1l,
    const u16* __restrict__ w2h, const u16* __restrict__ w2l,
    const float* __restrict__ b1f, const float* __restrict__ b2f,
    u16* __restrict__ outH, int dil,
    const float* __restrict__ x, int jvar, int jf,
    const u16* __restrict__ cwtbH, const u16* __restrict__ cwtbL,
    const float* __restrict__ cb, float* __restrict__ pacc,
    const float* __restrict__ vcw, const float* __restrict__ vcb,
    float* __restrict__ facc, float* __restrict__ fout) {
  __shared__ __align__(16) u16 lds[16384];   // 32768 B -> 5 blocks/CU
  u16* hH = lds;                             // [64 col][128] XOR-swizzled (16B blocks)
  u16* hL = lds + 8192;

  const int tid = threadIdx.x;
  const int lane = tid & 63;
  const int wid = __builtin_amdgcn_readfirstlane(tid >> 6);
  const int l15 = lane & 15;
  const int g = lane >> 4;
  const int col0 = blockIdx.x * 64;
  const int b = blockIdx.y;

  if (VAR) {
    int c = (int)x[b * 1025 + 1024];
    c = c < 0 ? 0 : (c > 3 ? 3 : c);
    c = __builtin_amdgcn_readfirstlane(c);
    const int lo_ = c * 2 + jvar;
    w1h += lo_ * 20480; w1l += lo_ * 20480;
    w2h += lo_ * 4096;  w2l += lo_ * 4096;
    b1f += lo_ * 128;   b2f += lo_ * 32;
  }

  const int co0 = wid * 32;
  const f4v zf = {0.f, 0.f, 0.f, 0.f};
  const s8v z8 = {0, 0, 0, 0, 0, 0, 0, 0};
  f4v acc[2][4];
#pragma unroll
  for (int rt = 0; rt < 2; ++rt)
#pragma unroll
    for (int ct = 0; ct < 4; ++ct) acc[rt][ct] = zf;

  if (S == 1) {
    // ---- stage 192-col act halo tile into LDS (slot-XOR swizzle) ----
    const u16* aH = (const u16*)src;
    const int gbase = (b * 1152 + col0) * 32;
#pragma unroll
    for (int k = 0; k < 3; ++k) {
      const int c2 = tid + k * 256;
      const int q = c2 >> 2, slot = c2 & 3;
      const uint4 v = *(const uint4*)(aH + gbase + c2 * 8);
      *(uint4*)&lds[q * 32 + ((slot ^ (q & 3)) << 3)] = v;
    }
#pragma unroll
    for (int k = 0; k < 3; ++k) {
      const int c2 = tid + k * 256;
      const int q = c2 >> 2, slot = c2 & 3;
      const uint4 v = *(const uint4*)(aH + ACT_PLANE + gbase + c2 * 8);
      *(uint4*)&lds[6144 + q * 32 + ((slot ^ (q & 3)) << 3)] = v;
    }
    __syncthreads();

#pragma unroll
    for (int tap = 0; tap < 5; ++tap) {
      s8v ah[2], al[2];
#pragma unroll
      for (int rt = 0; rt < 2; ++rt) {
        const int row = co0 + rt * 16 + l15;
        ah[rt] = *(const s8v*)(w1h + (tap * 128 + row) * 32 + 8 * g);
        al[rt] = *(const s8v*)(w1l + (tap * 128 + row) * 32 + 8 * g);
      }
#pragma unroll
      for (int ct = 0; ct < 4; ++ct) {
        const int q = ct * 16 + l15 + (tap - 2) * dil + 64;   // 0..191
        const int off = q * 32 + ((g ^ (q & 3)) << 3);
        const s8v bh = *(const s8v*)&lds[off];
        const s8v bl = *(const s8v*)&lds[6144 + off];
#pragma unroll
        for (int rt = 0; rt < 2; ++rt) {
          acc[rt][ct] = __builtin_amdgcn_mfma_f32_16x16x32_bf16(ah[rt], bh, acc[rt][ct], 0, 0, 0);
          acc[rt][ct] = __builtin_amdgcn_mfma_f32_16x16x32_bf16(ah[rt], bl, acc[rt][ct], 0, 0, 0);
          acc[rt][ct] = __builtin_amdgcn_mfma_f32_16x16x32_bf16(al[rt], bh, acc[rt][ct], 0, 0, 0);
        }
      }
    }
    __syncthreads();   // act tile dead; lds reused for h below
  } else if (S == 0) {
    // CIN=1: single k-step, k=q (5 valid taps), f32 source + split
    s8v ah[2], al[2];
#pragma unroll
    for (int rt = 0; rt < 2; ++rt) {
      const int row = co0 + rt * 16 + l15;
      ah[rt] = *(const s8v*)(w1h + row * 32 + 8 * g);
      al[rt] = *(const s8v*)(w1l + row * 32 + 8 * g);
    }
    const float* xf = (const float*)src;
#pragma unroll
    for (int ct = 0; ct < 4; ++ct) {
      s8v bh = z8, bl = z8;
#pragma unroll
      for (int j = 0; j < 8; ++j) {
        const int q = 8 * g + j;
        const int m = col0 + ct * 16 + l15 + (q - 2);
        float v = (q < 5 && (unsigned)m < 1024u) ? xf[b * 1025 + m] : 0.f;
        u16 hh, ll; splitf(v, hh, ll);
        bh[j] = (short)hh; bl[j] = (short)ll;
      }
#pragma unroll
      for (int rt = 0; rt < 2; ++rt) {
        acc[rt][ct] = __builtin_amdgcn_mfma_f32_16x16x32_bf16(ah[rt], bh, acc[rt][ct], 0, 0, 0);
        acc[rt][ct] = __builtin_amdgcn_mfma_f32_16x16x32_bf16(ah[rt], bl, acc[rt][ct], 0, 0, 0);
        acc[rt][ct] = __builtin_amdgcn_mfma_f32_16x16x32_bf16(al[rt], bh, acc[rt][ct], 0, 0, 0);
      }
    }
  } else {
    // CIN=64 from f32 pacc [b][512 pg][64 e], nearest-upsample.
    // Stage halo pcols [p0-32, p0+64) as bf16 hi/lo planes [96 s][64 e], XOR 16B blocks.
    const float* pc = (const float*)src;
    const int p0 = col0 >> 1;
#pragma unroll
    for (int k = 0; k < 24; ++k) {
      const int idx = tid + k * 256;          // 0..6143
      const int s = idx >> 6, e = idx & 63;
      const int pcol = p0 - 32 + s;
      const float v = ((unsigned)pcol < 512u) ? pc[b * 32768 + pcol * 64 + e] : 0.f;
      u16 hh, ll; splitf(v, hh, ll);
      const int off = s * 64 + (e ^ ((s & 7) << 3));
      lds[off] = hh; lds[6144 + off] = ll;
    }
    __syncthreads();

#pragma unroll
    for (int tap = 0; tap < 5; ++tap) {
#pragma unroll
      for (int ch = 0; ch < 2; ++ch) {
        s8v ah[2], al[2];
#pragma unroll
        for (int rt = 0; rt < 2; ++rt) {
          const int row = co0 + rt * 16 + l15;
          ah[rt] = *(const s8v*)(w1h + (tap * 128 + row) * 64 + ch * 32 + 8 * g);
          al[rt] = *(const s8v*)(w1l + (tap * 128 + row) * 64 + ch * 32 + 8 * g);
        }
#pragma unroll
        for (int ct = 0; ct < 4; ++ct) {
          const int m = col0 + ct * 16 + l15 + (tap - 2) * dil;
          const int sIdx = (m >> 1) - p0 + 32;    // 0..95; OOB pcols pre-zeroed
          const int off = sIdx * 64 + ((ch * 32 + 8 * g) ^ ((sIdx & 7) << 3));
          const s8v bh = *(const s8v*)&lds[off];
          const s8v bl = *(const s8v*)&lds[6144 + off];
#pragma unroll
          for (int rt = 0; rt < 2; ++rt) {
            acc[rt][ct] = __builtin_amdgcn_mfma_f32_16x16x32_bf16(ah[rt], bh, acc[rt][ct], 0, 0, 0);
            acc[rt][ct] = __builtin_amdgcn_mfma_f32_16x16x32_bf16(ah[rt], bl, acc[rt][ct], 0, 0, 0);
            acc[rt][ct] = __builtin_amdgcn_mfma_f32_16x16x32_bf16(al[rt], bh, acc[rt][ct], 0, 0, 0);
          }
        }
      }
    }
    __syncthreads();   // staged tile dead; lds reused for h below
  }

  // ---- h = relu(conv1 + b1) -> hi/lo planes in LDS [col][128], XOR-swizzled ----
#pragma unroll
  for (int rt = 0; rt < 2; ++rt) {
#pragma unroll
    for (int ct = 0; ct < 4; ++ct) {
      const int colw = ct * 16 + l15;
      unsigned ph0 = 0, ph1 = 0, pl0 = 0, pl1 = 0;
#pragma unroll
      for (int reg = 0; reg < 4; ++reg) {
        const int c2 = co0 + rt * 16 + 4 * g + reg;
        const float hv = fmaxf(acc[rt][ct][reg] + b1f[c2], 0.f);
        u16 hh, ll; splitf(hv, hh, ll);
        if (reg == 0)      { ph0 = hh;                  pl0 = ll; }
        else if (reg == 1) { ph0 |= (unsigned)hh << 16; pl0 |= (unsigned)ll << 16; }
        else if (reg == 2) { ph1 = hh;                  pl1 = ll; }
        else               { ph1 |= (unsigned)hh << 16; pl1 |= (unsigned)ll << 16; }
      }
      const int base = colw * 128 + ((co0 + rt * 16 + 4 * g) ^ ((colw & 7) << 3));
      *(uint2*)&hH[base] = make_uint2(ph0, ph1);
      *(uint2*)&hL[base] = make_uint2(pl0, pl1);
    }
  }
  __syncthreads();

  // ---- conv2 MFMA: wave handles its 16-col slice ----
  f4v acc2[2];
  acc2[0] = zf; acc2[1] = zf;
  const int colw2 = wid * 16 + l15;
#pragma unroll
  for (int ks = 0; ks < 4; ++ks) {
    const int k0 = ks * 32 + 8 * g;
    const int off2 = colw2 * 128 + (k0 ^ ((colw2 & 7) << 3));
    const s8v bh = *(const s8v*)&hH[off2];
    const s8v bl = *(const s8v*)&hL[off2];
#pragma unroll
    for (int rt = 0; rt < 2; ++rt) {
      const int row = rt * 16 + l15;
      const s8v ah2 = *(const s8v*)(w2h + row * 128 + k0);
      const s8v al2 = *(const s8v*)(w2l + row * 128 + k0);
      acc2[rt] = __builtin_amdgcn_mfma_f32_16x16x32_bf16(ah2, bh, acc2[rt], 0, 0, 0);
      acc2[rt] = __builtin_amdgcn_mfma_f32_16x16x32_bf16(ah2, bl, acc2[rt], 0, 0, 0);
      acc2[rt] = __builtin_amdgcn_mfma_f32_16x16x32_bf16(al2, bh, acc2[rt], 0, 0, 0);
    }
  }

  // ---- epilogue: act store (padded [b][1152][32] planes) + fused pacc/facc ----
  u16* outL = outH + ACT_PLANE;
  float vv[8];
#pragma unroll
  for (int rt = 0; rt < 2; ++rt) {
    unsigned ph0 = 0, ph1 = 0, pl0 = 0, pl1 = 0;
#pragma unroll
    for (int reg = 0; reg < 4; ++reg) {
      const int r = rt * 16 + 4 * g + reg;
      const float v = fmaxf(acc2[rt][reg] + b2f[r], 0.f);
      vv[rt * 4 + reg] = v;
      u16 hh, ll; splitf(v, hh, ll);
      if (reg == 0)      { ph0 = hh;                  pl0 = ll; }
      else if (reg == 1) { ph0 |= (unsigned)hh << 16; pl0 |= (unsigned)ll << 16; }
      else if (reg == 2) { ph1 = hh;                  pl1 = ll; }
      else               { ph1 |= (unsigned)hh << 16; pl1 |= (unsigned)ll << 16; }
    }
    if (EPI != 5) {
      const int ob = (b * 1152 + 64 + col0 + colw2) * 32 + rt * 16 + 4 * g;
      *(uint2*)&outH[ob] = make_uint2(ph0, ph1);
      *(uint2*)&outL[ob] = make_uint2(pl0, pl1);
    }
  }
  __syncthreads();   // conv2 LDS reads done; lds reusable

  if (EPI <= 2) {
    // pooled spool [32 p][r] hi/lo planes, stride 40
    u16* spH = lds;
    u16* spL = lds + 1280;
    float vx[8];
#pragma unroll
    for (int i = 0; i < 8; ++i) vx[i] = __shfl_xor(vv[i], 1);
    if (!(l15 & 1)) {
      const int pl = colw2 >> 1;
#pragma unroll
      for (int i = 0; i < 8; ++i) {
        const int rt = i >> 2, reg = i & 3;
        const int r = rt * 16 + 4 * g + reg;
        const float pv = 0.5f * (vv[i] + vx[i]);
        u16 hh, ll; splitf(pv, hh, ll);
        spH[pl * 40 + r] = hh; spL[pl * 40 + r] = ll;
      }
    }
    __syncthreads();
    const u16* cwH = cwtbH + jf * 32;
    const u16* cwL = cwtbL + jf * 32;
    const s8v aH = *(const s8v*)(cwH + (wid * 16 + l15) * 192 + 8 * g);
    const s8v aL = *(const s8v*)(cwL + (wid * 16 + l15) * 192 + 8 * g);
#pragma unroll
    for (int pt = 0; pt < 2; ++pt) {
      const s8v bH = *(const s8v*)(spH + (pt * 16 + l15) * 40 + 8 * g);
      const s8v bL = *(const s8v*)(spL + (pt * 16 + l15) * 40 + 8 * g);
      f4v p = zf;
      p = __builtin_amdgcn_mfma_f32_16x16x32_bf16(aH, bH, p, 0, 0, 0);
      p = __builtin_amdgcn_mfma_f32_16x16x32_bf16(aH, bL, p, 0, 0, 0);
      p = __builtin_amdgcn_mfma_f32_16x16x32_bf16(aL, bH, p, 0, 0, 0);
      // pacc [b][pg][e]: lane writes 4 consecutive e -> coalesced f32x4 RMW
      const int e0 = wid * 16 + 4 * g;
      const int pg = (col0 >> 1) + pt * 16 + l15;
      float* dst = pacc + b * 32768 + pg * 64 + e0;
      f4v old;
      if (EPI == 1) {
        old[0] = cb[e0]; old[1] = cb[e0 + 1]; old[2] = cb[e0 + 2]; old[3] = cb[e0 + 3];
      } else {
        old = *(const f4v*)dst;
      }
#pragma unroll
      for (int reg = 0; reg < 4; ++reg) p[reg] += old[reg];
      *(f4v*)dst = p;
    }
  } else {
    // facc: stage f32 tile [32 r][64 col], wave 0 reduces
    float* ft = (float*)lds;
#pragma unroll
    for (int i = 0; i < 8; ++i) {
      const int rt = i >> 2, reg = i & 3;
      const int r = rt * 16 + 4 * g + reg;
      ft[r * 64 + colw2] = vv[i];
    }
    __syncthreads();
    if (wid == 0) {
      int c = (int)x[b * 1025 + 1024];
      c = c < 0 ? 0 : (c > 3 ? 3 : c);
      c = __builtin_amdgcn_readfirstlane(c);
      const float* w = vcw + c * 192 + jf * 32;
      float a = 0.f;
#pragma unroll
      for (int r = 0; r < 32; ++r) a = fmaf(w[r], ft[r * 64 + lane], a);
      float* fd = facc + b * 1024 + col0 + lane;
      a += (EPI == 3) ? vcb[c] : *fd;
      if (EPI == 5) fout[b * 1024 + col0 + lane] = a;
      else          *fd = a;
    }
  }
}

extern "C" void kernel_launch(void* const* d_in, const int* in_sizes, int n_in,
                              void* d_out, int out_size, void* d_ws, size_t ws_size,
                              hipStream_t stream) {
  (void)in_sizes; (void)n_in; (void)out_size; (void)ws_size;
  Ptrs P;
  for (int i = 0; i < 25; ++i) P.p[i] = (const float*)d_in[i];
  const float* x = (const float*)d_in[0];
  float* ws = (float*)d_ws;
  float* pacc = ws + OFF_PACC;
  float* facc = ws + OFF_FACC;
  u16* A0 = (u16*)(ws + OFF_ACT0);
  u16* A1 = (u16*)(ws + OFF_ACT1);
  auto W1H = [&](int l) { return (const u16*)(ws + OFF_W1H) + w1_off16(l); };
  auto W1L = [&](int l) { return (const u16*)(ws + OFF_W1L) + w1_off16(l); };
  auto W2H = [&](int l) { return (const u16*)(ws + OFF_W2H) + l * 4096; };
  auto W2L = [&](int l) { return (const u16*)(ws + OFF_W2L) + l * 4096; };
  auto BB1 = [&](int l) { return (const float*)(ws + OFF_B1) + l * 128; };
  auto BB2 = [&](int l) { return (const float*)(ws + OFF_B2) + l * 32; };
  const u16* cwtbH = (const u16*)(ws + OFF_CWT);
  const u16* cwtbL = cwtbH + 12288;
  const float* cb = ws + OFF_CB;
  const float* vcw = ws + OFF_VCW;
  const float* vcb = ws + OFF_VCB;
  float* outp = (float*)d_out;

  prep_k<<<dim3(40, 8), dim3(256), 0, stream>>>(P, ws);

  const dim3 bg(16, 64), bt(256);

  // ---- encoder (pacc fused) ----
  blk_k<1, 0, false, 1><<<bg, bt, 0, stream>>>(x, W1H(0), W1L(0), W2H(0), W2L(0),
      BB1(0), BB2(0), A0, 1, x, 0, 0, cwtbH, cwtbL, cb, pacc, vcw, vcb, facc, outp);
  u16* cur = A0; u16* nxt = A1;
  for (int j = 1; j <= 5; ++j) {
    blk_k<32, 1, false, 2><<<bg, bt, 0, stream>>>(cur, W1H(j), W1L(j), W2H(j), W2L(j),
        BB1(j), BB2(j), nxt, 1 << j, x, 0, j, cwtbH, cwtbL, cb, pacc, vcw, vcb, facc, outp);
    u16* t = cur; cur = nxt; nxt = t;
  }
  // ---- fixed decoder (facc fused) ----
  blk_k<64, 2, false, 3><<<bg, bt, 0, stream>>>(pacc, W1H(6), W1L(6), W2H(6), W2L(6),
      BB1(6), BB2(6), A0, 32, x, 0, 0, cwtbH, cwtbL, cb, pacc, vcw, vcb, facc, outp);
  cur = A0; nxt = A1;
  for (int j = 1; j <= 3; ++j) {
    blk_k<32, 1, false, 4><<<bg, bt, 0, stream>>>(cur, W1H(6 + j), W1L(6 + j), W2H(6 + j),
        W2L(6 + j), BB1(6 + j), BB2(6 + j), nxt, 1 << (5 - j), x, 0, j,
        cwtbH, cwtbL, cb, pacc, vcw, vcb, facc, outp);
    u16* t = cur; cur = nxt; nxt = t;
  }
  // ---- variable decoder (per-sample weights, base = layer 10) ----
  blk_k<32, 1, true, 4><<<bg, bt, 0, stream>>>(cur, W1H(10), W1L(10), W2H(10), W2L(10),
      BB1(10), BB2(10), nxt, 2, x, 0, 4, cwtbH, cwtbL, cb, pacc, vcw, vcb, facc, outp);
  { u16* t = cur; cur = nxt; nxt = t; }
  blk_k<32, 1, true, 5><<<bg, bt, 0, stream>>>(cur, W1H(10), W1L(10), W2H(10), W2L(10),
      BB1(10), BB2(10), nxt, 1, x, 1, 5, cwtbH, cwtbL, cb, pacc, vcw, vcb, facc, outp);
}

// Round 13
// 351.694 us; speedup vs baseline: 3.4125x; 1.0548x over previous
//
#include <hip/hip_runtime.h>
#include <hip/hip_bf16.h>

typedef unsigned short u16;
typedef short s8v __attribute__((ext_vector_type(8)));   // 8 bf16 (4 VGPRs)
typedef float f4v __attribute__((ext_vector_type(4)));

// L=1024, B=64, K=5, C=128, R=32, E=64, NL=6, NV=2, NF=4, NC=4, POOL=2
// All inputs/outputs f32. 18 k5-conv layers: 0=enc0, 1..5=enc, 6=decf0, 7..9=decf, 10..17=decv[c][j]
// Weights split-bf16 (hi+lo). Inter-layer ACTIVATIONS single bf16 plane (r13):
//   conv1 S=1 = 2 MFMAs (wh*a + wl*a); x / pacc / h remain split (3 MFMAs).
// pacc layout [b][pg 512][e 64]; h-tile 32KB XOR-swizzled -> 5 blocks/CU.

struct Ptrs { const float* p[25]; };

__host__ __device__ inline int w1_off16(int l) {
  if (l == 0) return 0;                        // enc0: [128][32 qpad] = 4096
  if (l <= 5) return 4096 + (l - 1) * 20480;   // [5][128][32]
  if (l == 6) return 106496;                   // decf0: [5][128][64] = 40960
  if (l <= 9) return 147456 + (l - 7) * 20480;
  return 208896 + (l - 10) * 20480;            // decv -> ends 372736
}

enum : int {
  OFF_W1H = 0,          // u16 372736
  OFF_W1L = 186368,
  OFF_W2H = 372736,     // u16 18*32*128
  OFF_W2L = 409600,
  OFF_CWT = 446464,     // u16 cwtbH [64][192] then cwtbL [64][192]
  OFF_B1  = 458752,     // f32 18*128
  OFF_B2  = 461056,     // f32 18*32
  OFF_CB  = 461632,     // f32 64
  OFF_VCW = 461696,     // f32 4*192
  OFF_VCB = 462464,     // f32 4
  OFF_PACC = 524288,    // f32 [64][512 pg][64 e]
  OFF_FACC = 2621440,   // f32 [64][1024]
  OFF_ACT0 = 2752512,   // u16 [64][1152][32] single bf16 plane (4.7 MB)
  OFF_ACT1 = 3932160,   // same
};

__device__ __host__ inline int w1_cin(int l) { return l == 0 ? 1 : (l == 6 ? 64 : 32); }

__device__ inline const float* w1_src(const Ptrs& in, int l) {
  if (l == 0) return in.p[1];
  if (l <= 5) return in.p[5] + (l - 1) * 20480;
  if (l == 6) return in.p[11];
  if (l <= 9) return in.p[15] + (l - 7) * 20480;
  return in.p[19] + (l - 10) * 20480;
}
__device__ inline const float* w2_src(const Ptrs& in, int l) {
  if (l == 0) return in.p[3];
  if (l <= 5) return in.p[7] + (l - 1) * 4096;
  if (l == 6) return in.p[13];
  if (l <= 9) return in.p[17] + (l - 7) * 4096;
  return in.p[21] + (l - 10) * 4096;
}
__device__ inline const float* b1_src(const Ptrs& in, int l) {
  if (l == 0) return in.p[2];
  if (l <= 5) return in.p[6] + (l - 1) * 128;
  if (l == 6) return in.p[12];
  if (l <= 9) return in.p[16] + (l - 7) * 128;
  return in.p[20] + (l - 10) * 128;
}
__device__ inline const float* b2_src(const Ptrs& in, int l) {
  if (l == 0) return in.p[4];
  if (l <= 5) return in.p[8] + (l - 1) * 32;
  if (l == 6) return in.p[14];
  if (l <= 9) return in.p[18] + (l - 7) * 32;
  return in.p[22] + (l - 10) * 32;
}

__device__ inline u16 f2b(float v) {
  unsigned b = __float_as_uint(v);
  b += 0x7FFFu + ((b >> 16) & 1u);
  return (u16)(b >> 16);
}
__device__ inline float b2fl(u16 h) { return __uint_as_float((unsigned)h << 16); }
__device__ inline void splitf(float v, u16& h, u16& l) {
  h = f2b(v);
  l = f2b(v - b2fl(h));
}

// ---- weight prep + act pad zeroing: grid (40, 8) ----
__global__ __launch_bounds__(256) void prep_k(Ptrs in, float* __restrict__ ws) {
  const int job = blockIdx.x;
  const int sl = blockIdx.y;
  const int t = threadIdx.x;
  u16* w1h = (u16*)(ws + OFF_W1H);
  u16* w1l = (u16*)(ws + OFF_W1L);
  u16* w2h = (u16*)(ws + OFF_W2H);
  u16* w2l = (u16*)(ws + OFF_W2L);
  u16* cwH = (u16*)(ws + OFF_CWT);
  u16* cwL = cwH + 12288;
  if (job == 0) {
    if (sl == 0) {
      const float* src = w1_src(in, 0);
      for (int i = t; i < 4096; i += 256) {
        const int co = i >> 5, q = i & 31;
        const float v = (q < 5) ? src[co * 5 + q] : 0.f;
        u16 hh, ll; splitf(v, hh, ll);
        w1h[i] = hh; w1l[i] = ll;
      }
    }
  } else if (job < 18) {
    // w1 [Cout][Cin][5] -> [tap 5][co 128][ci cin]
    const int cin = w1_cin(job);
    const int lc = (cin == 64) ? 6 : 5;
    const float* src = w1_src(in, job);
    u16* dh = w1h + w1_off16(job);
    u16* dl = w1l + w1_off16(job);
    const int n = 5 * 128 * cin;
    for (int i = t + sl * 256; i < n; i += 2048) {
      const int tap = i >> (7 + lc);
      const int co = (i >> lc) & 127;
      const int ci = i & (cin - 1);
      u16 hh, ll; splitf(src[(co * cin + ci) * 5 + tap], hh, ll);
      dh[i] = hh; dl[i] = ll;
    }
  } else if (job < 36) {
    const int l = job - 18;
    const float* src = w2_src(in, l);
    for (int i = t + sl * 256; i < 4096; i += 2048) {
      u16 hh, ll; splitf(src[i], hh, ll);
      w2h[l * 4096 + i] = hh; w2l[l * 4096 + i] = ll;
    }
  } else if (job == 36) {
    const float* src = in.p[9];
    for (int i = t + sl * 256; i < 12288; i += 2048) {
      u16 hh, ll; splitf(src[i], hh, ll);
      cwH[i] = hh; cwL[i] = ll;
    }
  } else if (job == 37) {
    if (sl == 0) {
      for (int i = t; i < 18 * 128; i += 256) {
        const int l = i >> 7, r = i & 127;
        ws[OFF_B1 + i] = b1_src(in, l)[r];
      }
      for (int i = t; i < 18 * 32; i += 256) {
        const int l = i >> 5, r = i & 31;
        ws[OFF_B2 + i] = b2_src(in, l)[r];
      }
      for (int i = t; i < 64; i += 256) ws[OFF_CB + i] = in.p[10][i];
      for (int i = t; i < 768; i += 256) ws[OFF_VCW + i] = in.p[23][i];
      for (int i = t; i < 4; i += 256) ws[OFF_VCB + i] = in.p[24][i];
    }
  } else {
    // jobs 38/39: zero the pad columns of A0/A1 (single plane each)
    u16* A = (u16*)(ws + (job == 38 ? OFF_ACT0 : OFF_ACT1));
    const uint4 z = make_uint4(0, 0, 0, 0);
    for (int i = t; i < 4096; i += 256) {
      const int cid = sl * 4096 + i;           // 0..32767 chunks of 8 u16
      const int b = cid >> 9;
      const int r2 = cid & 511;
      const int pc = r2 >> 2;
      const int slot = r2 & 3;
      const int col = (pc < 64) ? pc : (1024 + pc);
      *(uint4*)&A[(b * 1152 + col) * 32 + slot * 8] = z;
    }
  }
}

// ---- fused block: conv k5 (CIN->128) + ReLU + 1x1 (128->32) + ReLU + epilogue ----
// S=0: f32 x [B][1025]; S=1: u16 act padded (single plane); S=2: f32 pacc [b][512][64] upsampled
// EPI: 1=pacc-init 2=pacc-accum 3=facc-init 4=facc-accum 5=facc+store-out
template <int CIN, int S, bool VAR, int EPI>
__global__ __launch_bounds__(256, 5) void blk_k(
    const void* __restrict__ src,
    const u16* __restrict__ w1h, const u16* __restrict__ w1l,
    const u16* __restrict__ w2h, const u16* __restrict__ w2l,
    const float* __restrict__ b1f, const float* __restrict__ b2f,
    u16* __restrict__ outH, int dil,
    const float* __restrict__ x, int jvar, int jf,
    const u16* __restrict__ cwtbH, const u16* __restrict__ cwtbL,
    const float* __restrict__ cb, float* __restrict__ pacc,
    const float* __restrict__ vcw, const float* __restrict__ vcb,
    float* __restrict__ facc, float* __restrict__ fout) {
  __shared__ __align__(16) u16 lds[16384];   // 32768 B -> 5 blocks/CU
  u16* hH = lds;                             // [64 col][128] XOR-swizzled (16B blocks)
  u16* hL = lds + 8192;

  const int tid = threadIdx.x;
  const int lane = tid & 63;
  const int wid = __builtin_amdgcn_readfirstlane(tid >> 6);
  const int l15 = lane & 15;
  const int g = lane >> 4;
  const int col0 = blockIdx.x * 64;
  const int b = blockIdx.y;

  if (VAR) {
    int c = (int)x[b * 1025 + 1024];
    c = c < 0 ? 0 : (c > 3 ? 3 : c);
    c = __builtin_amdgcn_readfirstlane(c);
    const int lo_ = c * 2 + jvar;
    w1h += lo_ * 20480; w1l += lo_ * 20480;
    w2h += lo_ * 4096;  w2l += lo_ * 4096;
    b1f += lo_ * 128;   b2f += lo_ * 32;
  }

  const int co0 = wid * 32;
  const f4v zf = {0.f, 0.f, 0.f, 0.f};
  const s8v z8 = {0, 0, 0, 0, 0, 0, 0, 0};
  f4v acc[2][4];
#pragma unroll
  for (int rt = 0; rt < 2; ++rt)
#pragma unroll
    for (int ct = 0; ct < 4; ++ct) acc[rt][ct] = zf;

  if (S == 1) {
    // ---- stage 192-col act halo tile (single plane) into LDS, slot-XOR swizzle ----
    const u16* aH = (const u16*)src;
    const int gbase = (b * 1152 + col0) * 32;
#pragma unroll
    for (int k = 0; k < 3; ++k) {
      const int c2 = tid + k * 256;              // 0..767
      const int q = c2 >> 2, slot = c2 & 3;
      const uint4 v = *(const uint4*)(aH + gbase + c2 * 8);
      *(uint4*)&lds[q * 32 + ((slot ^ (q & 3)) << 3)] = v;
    }
    __syncthreads();

#pragma unroll
    for (int tap = 0; tap < 5; ++tap) {
      s8v ah[2], al[2];
#pragma unroll
      for (int rt = 0; rt < 2; ++rt) {
        const int row = co0 + rt * 16 + l15;
        ah[rt] = *(const s8v*)(w1h + (tap * 128 + row) * 32 + 8 * g);
        al[rt] = *(const s8v*)(w1l + (tap * 128 + row) * 32 + 8 * g);
      }
#pragma unroll
      for (int ct = 0; ct < 4; ++ct) {
        const int q = ct * 16 + l15 + (tap - 2) * dil + 64;   // 0..191
        const int off = q * 32 + ((g ^ (q & 3)) << 3);
        const s8v bh = *(const s8v*)&lds[off];
#pragma unroll
        for (int rt = 0; rt < 2; ++rt) {
          acc[rt][ct] = __builtin_amdgcn_mfma_f32_16x16x32_bf16(ah[rt], bh, acc[rt][ct], 0, 0, 0);
          acc[rt][ct] = __builtin_amdgcn_mfma_f32_16x16x32_bf16(al[rt], bh, acc[rt][ct], 0, 0, 0);
        }
      }
    }
    __syncthreads();   // act tile dead; lds reused for h below
  } else if (S == 0) {
    // CIN=1: single k-step, k=q (5 valid taps), f32 source + split (3 MFMAs)
    s8v ah[2], al[2];
#pragma unroll
    for (int rt = 0; rt < 2; ++rt) {
      const int row = co0 + rt * 16 + l15;
      ah[rt] = *(const s8v*)(w1h + row * 32 + 8 * g);
      al[rt] = *(const s8v*)(w1l + row * 32 + 8 * g);
    }
    const float* xf = (const float*)src;
#pragma unroll
    for (int ct = 0; ct < 4; ++ct) {
      s8v bh = z8, bl = z8;
#pragma unroll
      for (int j = 0; j < 8; ++j) {
        const int q = 8 * g + j;
        const int m = col0 + ct * 16 + l15 + (q - 2);
        float v = (q < 5 && (unsigned)m < 1024u) ? xf[b * 1025 + m] : 0.f;
        u16 hh, ll; splitf(v, hh, ll);
        bh[j] = (short)hh; bl[j] = (short)ll;
      }
#pragma unroll
      for (int rt = 0; rt < 2; ++rt) {
        acc[rt][ct] = __builtin_amdgcn_mfma_f32_16x16x32_bf16(ah[rt], bh, acc[rt][ct], 0, 0, 0);
        acc[rt][ct] = __builtin_amdgcn_mfma_f32_16x16x32_bf16(ah[rt], bl, acc[rt][ct], 0, 0, 0);
        acc[rt][ct] = __builtin_amdgcn_mfma_f32_16x16x32_bf16(al[rt], bh, acc[rt][ct], 0, 0, 0);
      }
    }
  } else {
    // CIN=64 from f32 pacc [b][512 pg][64 e], nearest-upsample; staged split (3 MFMAs).
    const float* pc = (const float*)src;
    const int p0 = col0 >> 1;
#pragma unroll
    for (int k = 0; k < 24; ++k) {
      const int idx = tid + k * 256;          // 0..6143
      const int s = idx >> 6, e = idx & 63;
      const int pcol = p0 - 32 + s;
      const float v = ((unsigned)pcol < 512u) ? pc[b * 32768 + pcol * 64 + e] : 0.f;
      u16 hh, ll; splitf(v, hh, ll);
      const int off = s * 64 + (e ^ ((s & 7) << 3));
      lds[off] = hh; lds[6144 + off] = ll;
    }
    __syncthreads();

#pragma unroll
    for (int tap = 0; tap < 5; ++tap) {
#pragma unroll
      for (int ch = 0; ch < 2; ++ch) {
        s8v ah[2], al[2];
#pragma unroll
        for (int rt = 0; rt < 2; ++rt) {
          const int row = co0 + rt * 16 + l15;
          ah[rt] = *(const s8v*)(w1h + (tap * 128 + row) * 64 + ch * 32 + 8 * g);
          al[rt] = *(const s8v*)(w1l + (tap * 128 + row) * 64 + ch * 32 + 8 * g);
        }
#pragma unroll
        for (int ct = 0; ct < 4; ++ct) {
          const int m = col0 + ct * 16 + l15 + (tap - 2) * dil;
          const int sIdx = (m >> 1) - p0 + 32;    // 0..95; OOB pcols pre-zeroed
          const int off = sIdx * 64 + ((ch * 32 + 8 * g) ^ ((sIdx & 7) << 3));
          const s8v bh = *(const s8v*)&lds[off];
          const s8v bl = *(const s8v*)&lds[6144 + off];
#pragma unroll
          for (int rt = 0; rt < 2; ++rt) {
            acc[rt][ct] = __builtin_amdgcn_mfma_f32_16x16x32_bf16(ah[rt], bh, acc[rt][ct], 0, 0, 0);
            acc[rt][ct] = __builtin_amdgcn_mfma_f32_16x16x32_bf16(ah[rt], bl, acc[rt][ct], 0, 0, 0);
            acc[rt][ct] = __builtin_amdgcn_mfma_f32_16x16x32_bf16(al[rt], bh, acc[rt][ct], 0, 0, 0);
          }
        }
      }
    }
    __syncthreads();   // staged tile dead; lds reused for h below
  }

  // ---- h = relu(conv1 + b1) -> hi/lo planes in LDS [col][128], XOR-swizzled ----
#pragma unroll
  for (int rt = 0; rt < 2; ++rt) {
#pragma unroll
    for (int ct = 0; ct < 4; ++ct) {
      const int colw = ct * 16 + l15;
      unsigned ph0 = 0, ph1 = 0, pl0 = 0, pl1 = 0;
#pragma unroll
      for (int reg = 0; reg < 4; ++reg) {
        const int c2 = co0 + rt * 16 + 4 * g + reg;
        const float hv = fmaxf(acc[rt][ct][reg] + b1f[c2], 0.f);
        u16 hh, ll; splitf(hv, hh, ll);
        if (reg == 0)      { ph0 = hh;                  pl0 = ll; }
        else if (reg == 1) { ph0 |= (unsigned)hh << 16; pl0 |= (unsigned)ll << 16; }
        else if (reg == 2) { ph1 = hh;                  pl1 = ll; }
        else               { ph1 |= (unsigned)hh << 16; pl1 |= (unsigned)ll << 16; }
      }
      const int base = colw * 128 + ((co0 + rt * 16 + 4 * g) ^ ((colw & 7) << 3));
      *(uint2*)&hH[base] = make_uint2(ph0, ph1);
      *(uint2*)&hL[base] = make_uint2(pl0, pl1);
    }
  }
  __syncthreads();

  // ---- conv2 MFMA: wave handles its 16-col slice ----
  f4v acc2[2];
  acc2[0] = zf; acc2[1] = zf;
  const int colw2 = wid * 16 + l15;
#pragma unroll
  for (int ks = 0; ks < 4; ++ks) {
    const int k0 = ks * 32 + 8 * g;
    const int off2 = colw2 * 128 + (k0 ^ ((colw2 & 7) << 3));
    const s8v bh = *(const s8v*)&hH[off2];
    const s8v bl = *(const s8v*)&hL[off2];
#pragma unroll
    for (int rt = 0; rt < 2; ++rt) {
      const int row = rt * 16 + l15;
      const s8v ah2 = *(const s8v*)(w2h + row * 128 + k0);
      const s8v al2 = *(const s8v*)(w2l + row * 128 + k0);
      acc2[rt] = __builtin_amdgcn_mfma_f32_16x16x32_bf16(ah2, bh, acc2[rt], 0, 0, 0);
      acc2[rt] = __builtin_amdgcn_mfma_f32_16x16x32_bf16(ah2, bl, acc2[rt], 0, 0, 0);
      acc2[rt] = __builtin_amdgcn_mfma_f32_16x16x32_bf16(al2, bh, acc2[rt], 0, 0, 0);
    }
  }

  // ---- epilogue: act store (single bf16 plane) + fused pacc/facc ----
  float vv[8];
#pragma unroll
  for (int rt = 0; rt < 2; ++rt) {
    unsigned ph0 = 0, ph1 = 0;
#pragma unroll
    for (int reg = 0; reg < 4; ++reg) {
      const int r = rt * 16 + 4 * g + reg;
      const float v = fmaxf(acc2[rt][reg] + b2f[r], 0.f);
      vv[rt * 4 + reg] = v;
      const u16 hh = f2b(v);
      if (reg == 0)      ph0 = hh;
      else if (reg == 1) ph0 |= (unsigned)hh << 16;
      else if (reg == 2) ph1 = hh;
      else               ph1 |= (unsigned)hh << 16;
    }
    if (EPI != 5) {
      const int ob = (b * 1152 + 64 + col0 + colw2) * 32 + rt * 16 + 4 * g;
      *(uint2*)&outH[ob] = make_uint2(ph0, ph1);
    }
  }
  __syncthreads();   // conv2 LDS reads done; lds reusable

  if (EPI <= 2) {
    // pooled spool [32 p][r] hi/lo planes, stride 40
    u16* spH = lds;
    u16* spL = lds + 1280;
    float vx[8];
#pragma unroll
    for (int i = 0; i < 8; ++i) vx[i] = __shfl_xor(vv[i], 1);
    if (!(l15 & 1)) {
      const int pl = colw2 >> 1;
#pragma unroll
      for (int i = 0; i < 8; ++i) {
        const int rt = i >> 2, reg = i & 3;
        const int r = rt * 16 + 4 * g + reg;
        const float pv = 0.5f * (vv[i] + vx[i]);
        u16 hh, ll; splitf(pv, hh, ll);
        spH[pl * 40 + r] = hh; spL[pl * 40 + r] = ll;
      }
    }
    __syncthreads();
    const u16* cwH = cwtbH + jf * 32;
    const u16* cwL = cwtbL + jf * 32;
    const s8v aH = *(const s8v*)(cwH + (wid * 16 + l15) * 192 + 8 * g);
    const s8v aL = *(const s8v*)(cwL + (wid * 16 + l15) * 192 + 8 * g);
#pragma unroll
    for (int pt = 0; pt < 2; ++pt) {
      const s8v bH = *(const s8v*)(spH + (pt * 16 + l15) * 40 + 8 * g);
      const s8v bL = *(const s8v*)(spL + (pt * 16 + l15) * 40 + 8 * g);
      f4v p = zf;
      p = __builtin_amdgcn_mfma_f32_16x16x32_bf16(aH, bH, p, 0, 0, 0);
      p = __builtin_amdgcn_mfma_f32_16x16x32_bf16(aH, bL, p, 0, 0, 0);
      p = __builtin_amdgcn_mfma_f32_16x16x32_bf16(aL, bH, p, 0, 0, 0);
      const int e0 = wid * 16 + 4 * g;
      const int pg = (col0 >> 1) + pt * 16 + l15;
      float* dst = pacc + b * 32768 + pg * 64 + e0;
      f4v old;
      if (EPI == 1) {
        old[0] = cb[e0]; old[1] = cb[e0 + 1]; old[2] = cb[e0 + 2]; old[3] = cb[e0 + 3];
      } else {
        old = *(const f4v*)dst;
      }
#pragma unroll
      for (int reg = 0; reg < 4; ++reg) p[reg] += old[reg];
      *(f4v*)dst = p;
    }
  } else {
    // facc: stage f32 tile [32 r][64 col], wave 0 reduces
    float* ft = (float*)lds;
#pragma unroll
    for (int i = 0; i < 8; ++i) {
      const int rt = i >> 2, reg = i & 3;
      const int r = rt * 16 + 4 * g + reg;
      ft[r * 64 + colw2] = vv[i];
    }
    __syncthreads();
    if (wid == 0) {
      int c = (int)x[b * 1025 + 1024];
      c = c < 0 ? 0 : (c > 3 ? 3 : c);
      c = __builtin_amdgcn_readfirstlane(c);
      const float* w = vcw + c * 192 + jf * 32;
      float a = 0.f;
#pragma unroll
      for (int r = 0; r < 32; ++r) a = fmaf(w[r], ft[r * 64 + lane], a);
      float* fd = facc + b * 1024 + col0 + lane;
      a += (EPI == 3) ? vcb[c] : *fd;
      if (EPI == 5) fout[b * 1024 + col0 + lane] = a;
      else          *fd = a;
    }
  }
}

extern "C" void kernel_launch(void* const* d_in, const int* in_sizes, int n_in,
                              void* d_out, int out_size, void* d_ws, size_t ws_size,
                              hipStream_t stream) {
  (void)in_sizes; (void)n_in; (void)out_size; (void)ws_size;
  Ptrs P;
  for (int i = 0; i < 25; ++i) P.p[i] = (const float*)d_in[i];
  const float* x = (const float*)d_in[0];
  float* ws = (float*)d_ws;
  float* pacc = ws + OFF_PACC;
  float* facc = ws + OFF_FACC;
  u16* A0 = (u16*)(ws + OFF_ACT0);
  u16* A1 = (u16*)(ws + OFF_ACT1);
  auto W1H = [&](int l) { return (const u16*)(ws + OFF_W1H) + w1_off16(l); };
  auto W1L = [&](int l) { return (const u16*)(ws + OFF_W1L) + w1_off16(l); };
  auto W2H = [&](int l) { return (const u16*)(ws + OFF_W2H) + l * 4096; };
  auto W2L = [&](int l) { return (const u16*)(ws + OFF_W2L) + l * 4096; };
  auto BB1 = [&](int l) { return (const float*)(ws + OFF_B1) + l * 128; };
  auto BB2 = [&](int l) { return (const float*)(ws + OFF_B2) + l * 32; };
  const u16* cwtbH = (const u16*)(ws + OFF_CWT);
  const u16* cwtbL = cwtbH + 12288;
  const float* cb = ws + OFF_CB;
  const float* vcw = ws + OFF_VCW;
  const float* vcb = ws + OFF_VCB;
  float* outp = (float*)d_out;

  prep_k<<<dim3(40, 8), dim3(256), 0, stream>>>(P, ws);

  const dim3 bg(16, 64), bt(256);

  // ---- encoder (pacc fused) ----
  blk_k<1, 0, false, 1><<<bg, bt, 0, stream>>>(x, W1H(0), W1L(0), W2H(0), W2L(0),
      BB1(0), BB2(0), A0, 1, x, 0, 0, cwtbH, cwtbL, cb, pacc, vcw, vcb, facc, outp);
  u16* cur = A0; u16* nxt = A1;
  for (int j = 1; j <= 5; ++j) {
    blk_k<32, 1, false, 2><<<bg, bt, 0, stream>>>(cur, W1H(j), W1L(j), W2H(j), W2L(j),
        BB1(j), BB2(j), nxt, 1 << j, x, 0, j, cwtbH, cwtbL, cb, pacc, vcw, vcb, facc, outp);
    u16* t = cur; cur = nxt; nxt = t;
  }
  // ---- fixed decoder (facc fused) ----
  blk_k<64, 2, false, 3><<<bg, bt, 0, stream>>>(pacc, W1H(6), W1L(6), W2H(6), W2L(6),
      BB1(6), BB2(6), A0, 32, x, 0, 0, cwtbH, cwtbL, cb, pacc, vcw, vcb, facc, outp);
  cur = A0; nxt = A1;
  for (int j = 1; j <= 3; ++j) {
    blk_k<32, 1, false, 4><<<bg, bt, 0, stream>>>(cur, W1H(6 + j), W1L(6 + j), W2H(6 + j),
        W2L(6 + j), BB1(6 + j), BB2(6 + j), nxt, 1 << (5 - j), x, 0, j,
        cwtbH, cwtbL, cb, pacc, vcw, vcb, facc, outp);
    u16* t = cur; cur = nxt; nxt = t;
  }
  // ---- variable decoder (per-sample weights, base = layer 10) ----
  blk_k<32, 1, true, 4><<<bg, bt, 0, stream>>>(cur, W1H(10), W1L(10), W2H(10), W2L(10),
      BB1(10), BB2(10), nxt, 2, x, 0, 4, cwtbH, cwtbL, cb, pacc, vcw, vcb, facc, outp);
  { u16* t = cur; cur = nxt; nxt = t; }
  blk_k<32, 1, true, 5><<<bg, bt, 0, stream>>>(cur, W1H(10), W1L(10), W2H(10), W2L(10),
      BB1(10), BB2(10), nxt, 1, x, 1, 5, cwtbH, cwtbL, cb, pacc, vcw, vcb, facc, outp);
}

// Round 14
// 333.513 us; speedup vs baseline: 3.5986x; 1.0545x over previous
//
#include <hip/hip_runtime.h>
#include <hip/hip_bf16.h>

typedef unsigned short u16;
typedef short s8v __attribute__((ext_vector_type(8)));   // 8 bf16 (4 VGPRs)
typedef float f4v __attribute__((ext_vector_type(4)));

// L=1024, B=64, K=5, C=128, R=32, E=64, NL=6, NV=2, NF=4, NC=4, POOL=2
// All inputs/outputs f32. 18 k5-conv layers: 0=enc0, 1..5=enc, 6=decf0, 7..9=decf, 10..17=decv[c][j]
// Weights split-bf16 (hi+lo). Inter-layer activations single bf16 plane.
// r14: S=1 dynamic-halo staging (64+4*dil cols) + 2-deep w1-fragment pipeline.
// pacc layout [b][pg 512][e 64]; h-tile 32KB XOR-swizzled.

struct Ptrs { const float* p[25]; };

__host__ __device__ inline int w1_off16(int l) {
  if (l == 0) return 0;                        // enc0: [128][32 qpad] = 4096
  if (l <= 5) return 4096 + (l - 1) * 20480;   // [5][128][32]
  if (l == 6) return 106496;                   // decf0: [5][128][64] = 40960
  if (l <= 9) return 147456 + (l - 7) * 20480;
  return 208896 + (l - 10) * 20480;            // decv -> ends 372736
}

enum : int {
  OFF_W1H = 0,          // u16 372736
  OFF_W1L = 186368,
  OFF_W2H = 372736,     // u16 18*32*128
  OFF_W2L = 409600,
  OFF_CWT = 446464,     // u16 cwtbH [64][192] then cwtbL [64][192]
  OFF_B1  = 458752,     // f32 18*128
  OFF_B2  = 461056,     // f32 18*32
  OFF_CB  = 461632,     // f32 64
  OFF_VCW = 461696,     // f32 4*192
  OFF_VCB = 462464,     // f32 4
  OFF_PACC = 524288,    // f32 [64][512 pg][64 e]
  OFF_FACC = 2621440,   // f32 [64][1024]
  OFF_ACT0 = 2752512,   // u16 [64][1152][32] single bf16 plane
  OFF_ACT1 = 3932160,   // same
};

__device__ __host__ inline int w1_cin(int l) { return l == 0 ? 1 : (l == 6 ? 64 : 32); }

__device__ inline const float* w1_src(const Ptrs& in, int l) {
  if (l == 0) return in.p[1];
  if (l <= 5) return in.p[5] + (l - 1) * 20480;
  if (l == 6) return in.p[11];
  if (l <= 9) return in.p[15] + (l - 7) * 20480;
  return in.p[19] + (l - 10) * 20480;
}
__device__ inline const float* w2_src(const Ptrs& in, int l) {
  if (l == 0) return in.p[3];
  if (l <= 5) return in.p[7] + (l - 1) * 4096;
  if (l == 6) return in.p[13];
  if (l <= 9) return in.p[17] + (l - 7) * 4096;
  return in.p[21] + (l - 10) * 4096;
}
__device__ inline const float* b1_src(const Ptrs& in, int l) {
  if (l == 0) return in.p[2];
  if (l <= 5) return in.p[6] + (l - 1) * 128;
  if (l == 6) return in.p[12];
  if (l <= 9) return in.p[16] + (l - 7) * 128;
  return in.p[20] + (l - 10) * 128;
}
__device__ inline const float* b2_src(const Ptrs& in, int l) {
  if (l == 0) return in.p[4];
  if (l <= 5) return in.p[8] + (l - 1) * 32;
  if (l == 6) return in.p[14];
  if (l <= 9) return in.p[18] + (l - 7) * 32;
  return in.p[22] + (l - 10) * 32;
}

__device__ inline u16 f2b(float v) {
  unsigned b = __float_as_uint(v);
  b += 0x7FFFu + ((b >> 16) & 1u);
  return (u16)(b >> 16);
}
__device__ inline float b2fl(u16 h) { return __uint_as_float((unsigned)h << 16); }
__device__ inline void splitf(float v, u16& h, u16& l) {
  h = f2b(v);
  l = f2b(v - b2fl(h));
}

// ---- weight prep + act pad zeroing: grid (40, 8) ----
__global__ __launch_bounds__(256) void prep_k(Ptrs in, float* __restrict__ ws) {
  const int job = blockIdx.x;
  const int sl = blockIdx.y;
  const int t = threadIdx.x;
  u16* w1h = (u16*)(ws + OFF_W1H);
  u16* w1l = (u16*)(ws + OFF_W1L);
  u16* w2h = (u16*)(ws + OFF_W2H);
  u16* w2l = (u16*)(ws + OFF_W2L);
  u16* cwH = (u16*)(ws + OFF_CWT);
  u16* cwL = cwH + 12288;
  if (job == 0) {
    if (sl == 0) {
      const float* src = w1_src(in, 0);
      for (int i = t; i < 4096; i += 256) {
        const int co = i >> 5, q = i & 31;
        const float v = (q < 5) ? src[co * 5 + q] : 0.f;
        u16 hh, ll; splitf(v, hh, ll);
        w1h[i] = hh; w1l[i] = ll;
      }
    }
  } else if (job < 18) {
    // w1 [Cout][Cin][5] -> [tap 5][co 128][ci cin]
    const int cin = w1_cin(job);
    const int lc = (cin == 64) ? 6 : 5;
    const float* src = w1_src(in, job);
    u16* dh = w1h + w1_off16(job);
    u16* dl = w1l + w1_off16(job);
    const int n = 5 * 128 * cin;
    for (int i = t + sl * 256; i < n; i += 2048) {
      const int tap = i >> (7 + lc);
      const int co = (i >> lc) & 127;
      const int ci = i & (cin - 1);
      u16 hh, ll; splitf(src[(co * cin + ci) * 5 + tap], hh, ll);
      dh[i] = hh; dl[i] = ll;
    }
  } else if (job < 36) {
    const int l = job - 18;
    const float* src = w2_src(in, l);
    for (int i = t + sl * 256; i < 4096; i += 2048) {
      u16 hh, ll; splitf(src[i], hh, ll);
      w2h[l * 4096 + i] = hh; w2l[l * 4096 + i] = ll;
    }
  } else if (job == 36) {
    const float* src = in.p[9];
    for (int i = t + sl * 256; i < 12288; i += 2048) {
      u16 hh, ll; splitf(src[i], hh, ll);
      cwH[i] = hh; cwL[i] = ll;
    }
  } else if (job == 37) {
    if (sl == 0) {
      for (int i = t; i < 18 * 128; i += 256) {
        const int l = i >> 7, r = i & 127;
        ws[OFF_B1 + i] = b1_src(in, l)[r];
      }
      for (int i = t; i < 18 * 32; i += 256) {
        const int l = i >> 5, r = i & 31;
        ws[OFF_B2 + i] = b2_src(in, l)[r];
      }
      for (int i = t; i < 64; i += 256) ws[OFF_CB + i] = in.p[10][i];
      for (int i = t; i < 768; i += 256) ws[OFF_VCW + i] = in.p[23][i];
      for (int i = t; i < 4; i += 256) ws[OFF_VCB + i] = in.p[24][i];
    }
  } else {
    // jobs 38/39: zero the pad columns of A0/A1 (single plane each)
    u16* A = (u16*)(ws + (job == 38 ? OFF_ACT0 : OFF_ACT1));
    const uint4 z = make_uint4(0, 0, 0, 0);
    for (int i = t; i < 4096; i += 256) {
      const int cid = sl * 4096 + i;           // 0..32767 chunks of 8 u16
      const int b = cid >> 9;
      const int r2 = cid & 511;
      const int pc = r2 >> 2;
      const int slot = r2 & 3;
      const int col = (pc < 64) ? pc : (1024 + pc);
      *(uint4*)&A[(b * 1152 + col) * 32 + slot * 8] = z;
    }
  }
}

// ---- fused block: conv k5 (CIN->128) + ReLU + 1x1 (128->32) + ReLU + epilogue ----
// S=0: f32 x [B][1025]; S=1: u16 act padded (single plane); S=2: f32 pacc [b][512][64] upsampled
// EPI: 1=pacc-init 2=pacc-accum 3=facc-init 4=facc-accum 5=facc+store-out
template <int CIN, int S, bool VAR, int EPI>
__global__ __launch_bounds__(256, 4) void blk_k(
    const void* __restrict__ src,
    const u16* __restrict__ w1h, const u16* __restrict__ w1l,
    const u16* __restrict__ w2h, const u16* __restrict__ w2l,
    const float* __restrict__ b1f, const float* __restrict__ b2f,
    u16* __restrict__ outH, int dil,
    const float* __restrict__ x, int jvar, int jf,
    const u16* __restrict__ cwtbH, const u16* __restrict__ cwtbL,
    const float* __restrict__ cb, float* __restrict__ pacc,
    const float* __restrict__ vcw, const float* __restrict__ vcb,
    float* __restrict__ facc, float* __restrict__ fout) {
  __shared__ __align__(16) u16 lds[16384];   // 32768 B -> 5 blocks/CU
  u16* hH = lds;                             // [64 col][128] XOR-swizzled (16B blocks)
  u16* hL = lds + 8192;

  const int tid = threadIdx.x;
  const int lane = tid & 63;
  const int wid = __builtin_amdgcn_readfirstlane(tid >> 6);
  const int l15 = lane & 15;
  const int g = lane >> 4;
  const int col0 = blockIdx.x * 64;
  const int b = blockIdx.y;

  if (VAR) {
    int c = (int)x[b * 1025 + 1024];
    c = c < 0 ? 0 : (c > 3 ? 3 : c);
    c = __builtin_amdgcn_readfirstlane(c);
    const int lo_ = c * 2 + jvar;
    w1h += lo_ * 20480; w1l += lo_ * 20480;
    w2h += lo_ * 4096;  w2l += lo_ * 4096;
    b1f += lo_ * 128;   b2f += lo_ * 32;
  }

  const int co0 = wid * 32;
  const f4v zf = {0.f, 0.f, 0.f, 0.f};
  const s8v z8 = {0, 0, 0, 0, 0, 0, 0, 0};
  f4v acc[2][4];
#pragma unroll
  for (int rt = 0; rt < 2; ++rt)
#pragma unroll
    for (int ct = 0; ct < 4; ++ct) acc[rt][ct] = zf;

  if (S == 1) {
    // ---- dynamic-halo stage: cols [col0-2dil, col0+64+2dil) (padded coords), XOR swizzle ----
    const u16* aH = (const u16*)src;
    const int s0 = col0 + 64 - 2 * dil;        // >= 0 (dil <= 32)
    const int nchunk = (64 + 4 * dil) * 4;     // uint4 chunks, <= 768
    const u16* gsrc = aH + (b * 1152 + s0) * 32;
    uint4 sv0, sv1, sv2;
    if (tid < nchunk)       sv0 = *(const uint4*)(gsrc + tid * 8);
    if (tid + 256 < nchunk) sv1 = *(const uint4*)(gsrc + (tid + 256) * 8);
    if (tid + 512 < nchunk) sv2 = *(const uint4*)(gsrc + (tid + 512) * 8);

    // preload tap-0 w1 fragments while stage loads are in flight
    s8v ahp[2][2], alp[2][2];
#pragma unroll
    for (int rt = 0; rt < 2; ++rt) {
      const int row = co0 + rt * 16 + l15;
      ahp[0][rt] = *(const s8v*)(w1h + row * 32 + 8 * g);
      alp[0][rt] = *(const s8v*)(w1l + row * 32 + 8 * g);
    }

    if (tid < nchunk) {
      const int q = tid >> 2, sl = tid & 3;
      *(uint4*)&lds[q * 32 + ((sl ^ (q & 3)) << 3)] = sv0;
    }
    if (tid + 256 < nchunk) {
      const int c2 = tid + 256, q = c2 >> 2, sl = c2 & 3;
      *(uint4*)&lds[q * 32 + ((sl ^ (q & 3)) << 3)] = sv1;
    }
    if (tid + 512 < nchunk) {
      const int c2 = tid + 512, q = c2 >> 2, sl = c2 & 3;
      *(uint4*)&lds[q * 32 + ((sl ^ (q & 3)) << 3)] = sv2;
    }
    __syncthreads();

    // ---- conv1: 2-deep tap pipeline (load tap t+1 while MFMAing tap t) ----
#pragma unroll
    for (int tap = 0; tap < 5; ++tap) {
      const int cu = tap & 1, nx = (tap + 1) & 1;
      if (tap < 4) {
#pragma unroll
        for (int rt = 0; rt < 2; ++rt) {
          const int row = co0 + rt * 16 + l15;
          ahp[nx][rt] = *(const s8v*)(w1h + ((tap + 1) * 128 + row) * 32 + 8 * g);
          alp[nx][rt] = *(const s8v*)(w1l + ((tap + 1) * 128 + row) * 32 + 8 * g);
        }
      }
#pragma unroll
      for (int ct = 0; ct < 4; ++ct) {
        const int q = ct * 16 + l15 + tap * dil;   // relative to s0
        const int off = q * 32 + ((g ^ (q & 3)) << 3);
        const s8v bh = *(const s8v*)&lds[off];
#pragma unroll
        for (int rt = 0; rt < 2; ++rt) {
          acc[rt][ct] = __builtin_amdgcn_mfma_f32_16x16x32_bf16(ahp[cu][rt], bh, acc[rt][ct], 0, 0, 0);
          acc[rt][ct] = __builtin_amdgcn_mfma_f32_16x16x32_bf16(alp[cu][rt], bh, acc[rt][ct], 0, 0, 0);
        }
      }
    }
    __syncthreads();   // act tile dead; lds reused for h below
  } else if (S == 0) {
    // CIN=1: single k-step, k=q (5 valid taps), f32 source + split (3 MFMAs)
    s8v ah[2], al[2];
#pragma unroll
    for (int rt = 0; rt < 2; ++rt) {
      const int row = co0 + rt * 16 + l15;
      ah[rt] = *(const s8v*)(w1h + row * 32 + 8 * g);
      al[rt] = *(const s8v*)(w1l + row * 32 + 8 * g);
    }
    const float* xf = (const float*)src;
#pragma unroll
    for (int ct = 0; ct < 4; ++ct) {
      s8v bh = z8, bl = z8;
#pragma unroll
      for (int j = 0; j < 8; ++j) {
        const int q = 8 * g + j;
        const int m = col0 + ct * 16 + l15 + (q - 2);
        float v = (q < 5 && (unsigned)m < 1024u) ? xf[b * 1025 + m] : 0.f;
        u16 hh, ll; splitf(v, hh, ll);
        bh[j] = (short)hh; bl[j] = (short)ll;
      }
#pragma unroll
      for (int rt = 0; rt < 2; ++rt) {
        acc[rt][ct] = __builtin_amdgcn_mfma_f32_16x16x32_bf16(ah[rt], bh, acc[rt][ct], 0, 0, 0);
        acc[rt][ct] = __builtin_amdgcn_mfma_f32_16x16x32_bf16(ah[rt], bl, acc[rt][ct], 0, 0, 0);
        acc[rt][ct] = __builtin_amdgcn_mfma_f32_16x16x32_bf16(al[rt], bh, acc[rt][ct], 0, 0, 0);
      }
    }
  } else {
    // CIN=64 from f32 pacc [b][512 pg][64 e], nearest-upsample; staged split (3 MFMAs).
    const float* pc = (const float*)src;
    const int p0 = col0 >> 1;
#pragma unroll
    for (int k = 0; k < 24; ++k) {
      const int idx = tid + k * 256;          // 0..6143
      const int s = idx >> 6, e = idx & 63;
      const int pcol = p0 - 32 + s;
      const float v = ((unsigned)pcol < 512u) ? pc[b * 32768 + pcol * 64 + e] : 0.f;
      u16 hh, ll; splitf(v, hh, ll);
      const int off = s * 64 + (e ^ ((s & 7) << 3));
      lds[off] = hh; lds[6144 + off] = ll;
    }
    __syncthreads();

#pragma unroll
    for (int tap = 0; tap < 5; ++tap) {
#pragma unroll
      for (int ch = 0; ch < 2; ++ch) {
        s8v ah[2], al[2];
#pragma unroll
        for (int rt = 0; rt < 2; ++rt) {
          const int row = co0 + rt * 16 + l15;
          ah[rt] = *(const s8v*)(w1h + (tap * 128 + row) * 64 + ch * 32 + 8 * g);
          al[rt] = *(const s8v*)(w1l + (tap * 128 + row) * 64 + ch * 32 + 8 * g);
        }
#pragma unroll
        for (int ct = 0; ct < 4; ++ct) {
          const int m = col0 + ct * 16 + l15 + (tap - 2) * dil;
          const int sIdx = (m >> 1) - p0 + 32;    // 0..95; OOB pcols pre-zeroed
          const int off = sIdx * 64 + ((ch * 32 + 8 * g) ^ ((sIdx & 7) << 3));
          const s8v bh = *(const s8v*)&lds[off];
          const s8v bl = *(const s8v*)&lds[6144 + off];
#pragma unroll
          for (int rt = 0; rt < 2; ++rt) {
            acc[rt][ct] = __builtin_amdgcn_mfma_f32_16x16x32_bf16(ah[rt], bh, acc[rt][ct], 0, 0, 0);
            acc[rt][ct] = __builtin_amdgcn_mfma_f32_16x16x32_bf16(ah[rt], bl, acc[rt][ct], 0, 0, 0);
            acc[rt][ct] = __builtin_amdgcn_mfma_f32_16x16x32_bf16(al[rt], bh, acc[rt][ct], 0, 0, 0);
          }
        }
      }
    }
    __syncthreads();   // staged tile dead; lds reused for h below
  }

  // ---- h = relu(conv1 + b1) -> hi/lo planes in LDS [col][128], XOR-swizzled ----
#pragma unroll
  for (int rt = 0; rt < 2; ++rt) {
#pragma unroll
    for (int ct = 0; ct < 4; ++ct) {
      const int colw = ct * 16 + l15;
      unsigned ph0 = 0, ph1 = 0, pl0 = 0, pl1 = 0;
#pragma unroll
      for (int reg = 0; reg < 4; ++reg) {
        const int c2 = co0 + rt * 16 + 4 * g + reg;
        const float hv = fmaxf(acc[rt][ct][reg] + b1f[c2], 0.f);
        u16 hh, ll; splitf(hv, hh, ll);
        if (reg == 0)      { ph0 = hh;                  pl0 = ll; }
        else if (reg == 1) { ph0 |= (unsigned)hh << 16; pl0 |= (unsigned)ll << 16; }
        else if (reg == 2) { ph1 = hh;                  pl1 = ll; }
        else               { ph1 |= (unsigned)hh << 16; pl1 |= (unsigned)ll << 16; }
      }
      const int base = colw * 128 + ((co0 + rt * 16 + 4 * g) ^ ((colw & 7) << 3));
      *(uint2*)&hH[base] = make_uint2(ph0, ph1);
      *(uint2*)&hL[base] = make_uint2(pl0, pl1);
    }
  }
  __syncthreads();

  // ---- conv2 MFMA: wave handles its 16-col slice ----
  f4v acc2[2];
  acc2[0] = zf; acc2[1] = zf;
  const int colw2 = wid * 16 + l15;
#pragma unroll
  for (int ks = 0; ks < 4; ++ks) {
    const int k0 = ks * 32 + 8 * g;
    const int off2 = colw2 * 128 + (k0 ^ ((colw2 & 7) << 3));
    const s8v bh = *(const s8v*)&hH[off2];
    const s8v bl = *(const s8v*)&hL[off2];
#pragma unroll
    for (int rt = 0; rt < 2; ++rt) {
      const int row = rt * 16 + l15;
      const s8v ah2 = *(const s8v*)(w2h + row * 128 + k0);
      const s8v al2 = *(const s8v*)(w2l + row * 128 + k0);
      acc2[rt] = __builtin_amdgcn_mfma_f32_16x16x32_bf16(ah2, bh, acc2[rt], 0, 0, 0);
      acc2[rt] = __builtin_amdgcn_mfma_f32_16x16x32_bf16(ah2, bl, acc2[rt], 0, 0, 0);
      acc2[rt] = __builtin_amdgcn_mfma_f32_16x16x32_bf16(al2, bh, acc2[rt], 0, 0, 0);
    }
  }

  // ---- epilogue: act store (single bf16 plane) + fused pacc/facc ----
  float vv[8];
#pragma unroll
  for (int rt = 0; rt < 2; ++rt) {
    unsigned ph0 = 0, ph1 = 0;
#pragma unroll
    for (int reg = 0; reg < 4; ++reg) {
      const int r = rt * 16 + 4 * g + reg;
      const float v = fmaxf(acc2[rt][reg] + b2f[r], 0.f);
      vv[rt * 4 + reg] = v;
      const u16 hh = f2b(v);
      if (reg == 0)      ph0 = hh;
      else if (reg == 1) ph0 |= (unsigned)hh << 16;
      else if (reg == 2) ph1 = hh;
      else               ph1 |= (unsigned)hh << 16;
    }
    if (EPI != 5) {
      const int ob = (b * 1152 + 64 + col0 + colw2) * 32 + rt * 16 + 4 * g;
      *(uint2*)&outH[ob] = make_uint2(ph0, ph1);
    }
  }
  __syncthreads();   // conv2 LDS reads done; lds reusable

  if (EPI <= 2) {
    // pooled spool [32 p][r] hi/lo planes, stride 40
    u16* spH = lds;
    u16* spL = lds + 1280;
    float vx[8];
#pragma unroll
    for (int i = 0; i < 8; ++i) vx[i] = __shfl_xor(vv[i], 1);
    if (!(l15 & 1)) {
      const int pl = colw2 >> 1;
#pragma unroll
      for (int i = 0; i < 8; ++i) {
        const int rt = i >> 2, reg = i & 3;
        const int r = rt * 16 + 4 * g + reg;
        const float pv = 0.5f * (vv[i] + vx[i]);
        u16 hh, ll; splitf(pv, hh, ll);
        spH[pl * 40 + r] = hh; spL[pl * 40 + r] = ll;
      }
    }
    __syncthreads();
    const u16* cwH = cwtbH + jf * 32;
    const u16* cwL = cwtbL + jf * 32;
    const s8v aH = *(const s8v*)(cwH + (wid * 16 + l15) * 192 + 8 * g);
    const s8v aL = *(const s8v*)(cwL + (wid * 16 + l15) * 192 + 8 * g);
#pragma unroll
    for (int pt = 0; pt < 2; ++pt) {
      const s8v bH = *(const s8v*)(spH + (pt * 16 + l15) * 40 + 8 * g);
      const s8v bL = *(const s8v*)(spL + (pt * 16 + l15) * 40 + 8 * g);
      f4v p = zf;
      p = __builtin_amdgcn_mfma_f32_16x16x32_bf16(aH, bH, p, 0, 0, 0);
      p = __builtin_amdgcn_mfma_f32_16x16x32_bf16(aH, bL, p, 0, 0, 0);
      p = __builtin_amdgcn_mfma_f32_16x16x32_bf16(aL, bH, p, 0, 0, 0);
      const int e0 = wid * 16 + 4 * g;
      const int pg = (col0 >> 1) + pt * 16 + l15;
      float* dst = pacc + b * 32768 + pg * 64 + e0;
      f4v old;
      if (EPI == 1) {
        old[0] = cb[e0]; old[1] = cb[e0 + 1]; old[2] = cb[e0 + 2]; old[3] = cb[e0 + 3];
      } else {
        old = *(const f4v*)dst;
      }
#pragma unroll
      for (int reg = 0; reg < 4; ++reg) p[reg] += old[reg];
      *(f4v*)dst = p;
    }
  } else {
    // facc: stage f32 tile [32 r][64 col], wave 0 reduces
    float* ft = (float*)lds;
#pragma unroll
    for (int i = 0; i < 8; ++i) {
      const int rt = i >> 2, reg = i & 3;
      const int r = rt * 16 + 4 * g + reg;
      ft[r * 64 + colw2] = vv[i];
    }
    __syncthreads();
    if (wid == 0) {
      int c = (int)x[b * 1025 + 1024];
      c = c < 0 ? 0 : (c > 3 ? 3 : c);
      c = __builtin_amdgcn_readfirstlane(c);
      const float* w = vcw + c * 192 + jf * 32;
      float a = 0.f;
#pragma unroll
      for (int r = 0; r < 32; ++r) a = fmaf(w[r], ft[r * 64 + lane], a);
      float* fd = facc + b * 1024 + col0 + lane;
      a += (EPI == 3) ? vcb[c] : *fd;
      if (EPI == 5) fout[b * 1024 + col0 + lane] = a;
      else          *fd = a;
    }
  }
}

extern "C" void kernel_launch(void* const* d_in, const int* in_sizes, int n_in,
                              void* d_out, int out_size, void* d_ws, size_t ws_size,
                              hipStream_t stream) {
  (void)in_sizes; (void)n_in; (void)out_size; (void)ws_size;
  Ptrs P;
  for (int i = 0; i < 25; ++i) P.p[i] = (const float*)d_in[i];
  const float* x = (const float*)d_in[0];
  float* ws = (float*)d_ws;
  float* pacc = ws + OFF_PACC;
  float* facc = ws + OFF_FACC;
  u16* A0 = (u16*)(ws + OFF_ACT0);
  u16* A1 = (u16*)(ws + OFF_ACT1);
  auto W1H = [&](int l) { return (const u16*)(ws + OFF_W1H) + w1_off16(l); };
  auto W1L = [&](int l) { return (const u16*)(ws + OFF_W1L) + w1_off16(l); };
  auto W2H = [&](int l) { return (const u16*)(ws + OFF_W2H) + l * 4096; };
  auto W2L = [&](int l) { return (const u16*)(ws + OFF_W2L) + l * 4096; };
  auto BB1 = [&](int l) { return (const float*)(ws + OFF_B1) + l * 128; };
  auto BB2 = [&](int l) { return (const float*)(ws + OFF_B2) + l * 32; };
  const u16* cwtbH = (const u16*)(ws + OFF_CWT);
  const u16* cwtbL = cwtbH + 12288;
  const float* cb = ws + OFF_CB;
  const float* vcw = ws + OFF_VCW;
  const float* vcb = ws + OFF_VCB;
  float* outp = (float*)d_out;

  prep_k<<<dim3(40, 8), dim3(256), 0, stream>>>(P, ws);

  const dim3 bg(16, 64), bt(256);

  // ---- encoder (pacc fused) ----
  blk_k<1, 0, false, 1><<<bg, bt, 0, stream>>>(x, W1H(0), W1L(0), W2H(0), W2L(0),
      BB1(0), BB2(0), A0, 1, x, 0, 0, cwtbH, cwtbL, cb, pacc, vcw, vcb, facc, outp);
  u16* cur = A0; u16* nxt = A1;
  for (int j = 1; j <= 5; ++j) {
    blk_k<32, 1, false, 2><<<bg, bt, 0, stream>>>(cur, W1H(j), W1L(j), W2H(j), W2L(j),
        BB1(j), BB2(j), nxt, 1 << j, x, 0, j, cwtbH, cwtbL, cb, pacc, vcw, vcb, facc, outp);
    u16* t = cur; cur = nxt; nxt = t;
  }
  // ---- fixed decoder (facc fused) ----
  blk_k<64, 2, false, 3><<<bg, bt, 0, stream>>>(pacc, W1H(6), W1L(6), W2H(6), W2L(6),
      BB1(6), BB2(6), A0, 32, x, 0, 0, cwtbH, cwtbL, cb, pacc, vcw, vcb, facc, outp);
  cur = A0; nxt = A1;
  for (int j = 1; j <= 3; ++j) {
    blk_k<32, 1, false, 4><<<bg, bt, 0, stream>>>(cur, W1H(6 + j), W1L(6 + j), W2H(6 + j),
        W2L(6 + j), BB1(6 + j), BB2(6 + j), nxt, 1 << (5 - j), x, 0, j,
        cwtbH, cwtbL, cb, pacc, vcw, vcb, facc, outp);
    u16* t = cur; cur = nxt; nxt = t;
  }
  // ---- variable decoder (per-sample weights, base = layer 10) ----
  blk_k<32, 1, true, 4><<<bg, bt, 0, stream>>>(cur, W1H(10), W1L(10), W2H(10), W2L(10),
      BB1(10), BB2(10), nxt, 2, x, 0, 4, cwtbH, cwtbL, cb, pacc, vcw, vcb, facc, outp);
  { u16* t = cur; cur = nxt; nxt = t; }
  blk_k<32, 1, true, 5><<<bg, bt, 0, stream>>>(cur, W1H(10), W1L(10), W2H(10), W2L(10),
      BB1(10), BB2(10), nxt, 1, x, 1, 5, cwtbH, cwtbL, cb, pacc, vcw, vcb, facc, outp);
}